// Round 8
// baseline (167.662 us; speedup 1.0000x reference)
//
#include <hip/hip_runtime.h>
#include <hip/hip_bf16.h>

typedef unsigned short u16;
typedef __attribute__((ext_vector_type(8))) __bf16 bf16x8;
typedef __attribute__((ext_vector_type(4))) float f32x4;

// Fragment-chunk layout for Qt/Kt/Vm (per batch, 4096x64 u16):
//   element (row n, channel c) -> ((n>>4)*8 + (c>>3))*128 + (n&15)*8 + (c&7)
// MFMA fragment loads are 64 consecutive 16B chunks -> coalesced dwordx4.

__device__ __forceinline__ u16 f2bf(float f) {
    unsigned u = __builtin_bit_cast(unsigned, f);
    u += 0x7FFFu + ((u >> 16) & 1u);
    return (u16)(u >> 16);
}
__device__ __forceinline__ float bf2f(u16 v) {
    unsigned u = ((unsigned)v) << 16;
    return __builtin_bit_cast(float, u);
}

// ------------------------------------------------------------ qkv + edge ---
// grid 512:
//  bid<256:  qkv  — LDS-staged W(bf16) + x-transpose, 24 MFMAs; Q scaled by
//            log2e (attn uses exp2); fragment-chunk layout outputs
//  bid>=256: edge — vectorized staging of 3 x-rows + We1 reorder, 36 MFMAs
__global__ __launch_bounds__(256) void qkv_edge_kernel(
    const float* __restrict__ x,
    const float* __restrict__ Wq, const float* __restrict__ bq,
    const float* __restrict__ Wk, const float* __restrict__ bk,
    const float* __restrict__ Wv, const float* __restrict__ bv,
    const float* __restrict__ We1, const float* __restrict__ be1,
    const float* __restrict__ bn_w, const float* __restrict__ bn_b,
    const float* __restrict__ bn_mean, const float* __restrict__ bn_var,
    const float* __restrict__ We2, const float* __restrict__ be2,
    const float* __restrict__ beta,
    u16* __restrict__ Qt, u16* __restrict__ Kt, u16* __restrict__ Vm,
    float* __restrict__ wkey)
{
    __shared__ __align__(16) u16 sm[33280];
    const int t = threadIdx.x;
    const int wv = t >> 6, lane = t & 63;
    const int quad = lane >> 4, l15 = lane & 15;

    if (blockIdx.x < 256) {
        // ---------------- qkv ----------------
        u16* Wl   = sm;                 // [3][64][72]
        u16* xt_s = sm + 13824;         // [64][66]
        u16* vt   = sm + 13824 + 4224;  // [64][72]
        const int b = blockIdx.x >> 6;
        const int n0 = (blockIdx.x & 63) << 6;

        const float* Wmat[3] = {Wq, Wk, Wv};
#pragma unroll
        for (int m = 0; m < 3; ++m)
#pragma unroll
            for (int i = 0; i < 4; ++i) {
                int u = t + i * 256;                  // 1024 units x 4 floats
                float4 w4 = *reinterpret_cast<const float4*>(Wmat[m] + u * 4);
                int row = u >> 4, col = (u & 15) * 4;
                uint2 pk;
                pk.x = (unsigned)f2bf(w4.x) | ((unsigned)f2bf(w4.y) << 16);
                pk.y = (unsigned)f2bf(w4.z) | ((unsigned)f2bf(w4.w) << 16);
                *reinterpret_cast<uint2*>(&Wl[(m * 64 + row) * 72 + col]) = pk;
            }
        for (int i = 0; i < 16; ++i) {
            int lin = t + i * 256;
            int c = lin >> 6, nn = lin & 63;
            xt_s[nn * 66 + c] = f2bf(x[(size_t)(b * 64 + c) * 4096 + n0 + nn]);
        }
        __syncthreads();

        bf16x8 bx[2];
#pragma unroll
        for (int h = 0; h < 2; ++h)
            bx[h] = *reinterpret_cast<const bf16x8*>(
                &xt_s[(wv * 16 + l15) * 66 + h * 32 + quad * 8]);

        f32x4 d[3][4];
#pragma unroll
        for (int m = 0; m < 3; ++m)
#pragma unroll
            for (int mt = 0; mt < 4; ++mt) d[m][mt] = (f32x4){0.f, 0.f, 0.f, 0.f};

#pragma unroll
        for (int h = 0; h < 2; ++h)
#pragma unroll
            for (int m = 0; m < 3; ++m)
#pragma unroll
                for (int mt = 0; mt < 4; ++mt) {
                    bf16x8 af = *reinterpret_cast<const bf16x8*>(
                        &Wl[(m * 64 + mt * 16 + l15) * 72 + h * 32 + quad * 8]);
                    d[m][mt] = __builtin_amdgcn_mfma_f32_16x16x32_bf16(af, bx[h], d[m][mt], 0, 0, 0);
                }

        const float* bias[3] = {bq, bk, bv};
        const float L2E = 1.44269504f;
#pragma unroll
        for (int m = 0; m < 3; ++m)
#pragma unroll
            for (int mt = 0; mt < 4; ++mt) {
                float4 bi = *reinterpret_cast<const float4*>(bias[m] + mt * 16 + quad * 4);
                d[m][mt][0] += bi.x; d[m][mt][1] += bi.y; d[m][mt][2] += bi.z; d[m][mt][3] += bi.w;
                if (m == 0) {
                    d[m][mt][0] *= L2E; d[m][mt][1] *= L2E;
                    d[m][mt][2] *= L2E; d[m][mt][3] *= L2E;
                }
            }

        const int rowchunk = (n0 >> 4) + wv;
#pragma unroll
        for (int m = 0; m < 2; ++m) {
            u16* base = (m == 0 ? Qt : Kt) + (size_t)b * 262144;
#pragma unroll
            for (int mt = 0; mt < 4; ++mt) {
                uint2 pk;
                pk.x = (unsigned)f2bf(d[m][mt][0]) | ((unsigned)f2bf(d[m][mt][1]) << 16);
                pk.y = (unsigned)f2bf(d[m][mt][2]) | ((unsigned)f2bf(d[m][mt][3]) << 16);
                *reinterpret_cast<uint2*>(
                    base + ((size_t)(rowchunk * 8 + mt * 2 + (quad >> 1))) * 128 +
                    l15 * 8 + (quad & 1) * 4) = pk;
            }
        }
#pragma unroll
        for (int mt = 0; mt < 4; ++mt)
#pragma unroll
            for (int r = 0; r < 4; ++r)
                vt[(mt * 16 + quad * 4 + r) * 72 + wv * 16 + l15] = f2bf(d[2][mt][r]);
        __syncthreads();
        {
            u16* Vb_st = Vm + (size_t)b * 262144;
            const int kt = n0 >> 6;
#pragma unroll
            for (int i = 0; i < 2; ++i) {
                int unit = t + i * 256;
                int f = unit >> 7, hq = (unit >> 4) & 7, cl = unit & 15;
                const u16* src = &vt[(f * 16 + cl) * 72 + hq * 8];
                uint4 v4 = *reinterpret_cast<const uint4*>(src);
                *reinterpret_cast<uint4*>(
                    Vb_st + ((size_t)((kt * 4 + f) * 8 + hq)) * 128 + cl * 8) = v4;
            }
        }
    } else {
        // ---------------- edge ----------------
        u16* Ae_s = sm;            // [32][584]
        u16* xr_s = sm + 18688;    // [3][66][72]
        const int eb = blockIdx.x - 256;
        const int b = eb >> 6, h = eb & 63;

        if (t < 192) {
            int kh = t / 64, rem = t & 63;
            int col = (rem >> 5) * 65, ci2 = (rem & 31) * 2;
            *reinterpret_cast<unsigned*>(&xr_s[(kh * 66 + col) * 72 + ci2]) = 0u;
        }
        // We1 (ch,ci,p) -> Ae_s[ch][p][ci], 4 ci per unit, ds_write_b64
#pragma unroll
        for (int i = 0; i < 18; ++i) {
            int u = t + i * 256;                 // 4608 units
            int ch = u / 144;
            int rem = u - ch * 144;
            int p = rem >> 4, cig = (rem & 15) * 4;
            const float* src = We1 + ch * 576 + cig * 9 + p;
            float a = src[0], b2 = src[9], c2 = src[18], d2 = src[27];
            uint2 pk;
            pk.x = (unsigned)f2bf(a) | ((unsigned)f2bf(b2) << 16);
            pk.y = (unsigned)f2bf(c2) | ((unsigned)f2bf(d2) << 16);
            *reinterpret_cast<uint2*>(&Ae_s[ch * 584 + p * 64 + cig]) = pk;
        }
        // x rows -> xr_s[kh][w+1][ci], 4 ci per unit, ds_write_b64
#pragma unroll
        for (int i = 0; i < 12; ++i) {
            int u = t + i * 256;                 // 3072 units
            int w = u & 63, cig = (u >> 6) & 15, kh = u >> 10;
            int hs = h + kh - 1;
            float v0 = 0.f, v1 = 0.f, v2 = 0.f, v3 = 0.f;
            if ((unsigned)hs < 64u) {
                const float* src = x + ((size_t)(b * 64 + cig * 4) * 64 + hs) * 64 + w;
                v0 = src[0]; v1 = src[4096]; v2 = src[8192]; v3 = src[12288];
            }
            uint2 pk;
            pk.x = (unsigned)f2bf(v0) | ((unsigned)f2bf(v1) << 16);
            pk.y = (unsigned)f2bf(v2) | ((unsigned)f2bf(v3) << 16);
            *reinterpret_cast<uint2*>(&xr_s[(kh * 66 + w + 1) * 72 + cig * 4]) = pk;
        }
        __syncthreads();

        f32x4 e[2];
        e[0] = (f32x4){0.f, 0.f, 0.f, 0.f};
        e[1] = (f32x4){0.f, 0.f, 0.f, 0.f};
#pragma unroll
        for (int p = 0; p < 9; ++p) {
            const int kh = p / 3, kw = p - kh * 3;
#pragma unroll
            for (int half = 0; half < 2; ++half) {
                bf16x8 bfr = *reinterpret_cast<const bf16x8*>(
                    &xr_s[(kh * 66 + wv * 16 + l15 + kw) * 72 + half * 32 + quad * 8]);
#pragma unroll
                for (int mt = 0; mt < 2; ++mt) {
                    bf16x8 af = *reinterpret_cast<const bf16x8*>(
                        &Ae_s[(mt * 16 + l15) * 584 + p * 64 + half * 32 + quad * 8]);
                    e[mt] = __builtin_amdgcn_mfma_f32_16x16x32_bf16(af, bfr, e[mt], 0, 0, 0);
                }
            }
        }
        float partial = 0.f;
#pragma unroll
        for (int mt = 0; mt < 2; ++mt) {
            float4 bw = *reinterpret_cast<const float4*>(bn_w    + mt * 16 + quad * 4);
            float4 bb = *reinterpret_cast<const float4*>(bn_b    + mt * 16 + quad * 4);
            float4 bm = *reinterpret_cast<const float4*>(bn_mean + mt * 16 + quad * 4);
            float4 bv2 = *reinterpret_cast<const float4*>(bn_var + mt * 16 + quad * 4);
            float4 b1 = *reinterpret_cast<const float4*>(be1     + mt * 16 + quad * 4);
            float4 w2 = *reinterpret_cast<const float4*>(We2     + mt * 16 + quad * 4);
            float sc, sh;
            sc = bw.x * rsqrtf(bv2.x + 1e-5f); sh = (b1.x - bm.x) * sc + bb.x;
            partial += fmaxf(e[mt][0] * sc + sh, 0.f) * w2.x;
            sc = bw.y * rsqrtf(bv2.y + 1e-5f); sh = (b1.y - bm.y) * sc + bb.y;
            partial += fmaxf(e[mt][1] * sc + sh, 0.f) * w2.y;
            sc = bw.z * rsqrtf(bv2.z + 1e-5f); sh = (b1.z - bm.z) * sc + bb.z;
            partial += fmaxf(e[mt][2] * sc + sh, 0.f) * w2.z;
            sc = bw.w * rsqrtf(bv2.w + 1e-5f); sh = (b1.w - bm.w) * sc + bb.w;
            partial += fmaxf(e[mt][3] * sc + sh, 0.f) * w2.w;
        }
        partial += __shfl_xor(partial, 16);
        partial += __shfl_xor(partial, 32);
        if (lane < 16) {
            float s = partial + be2[0];
            float sg = 1.f / (1.f + __expf(-s));
            wkey[(size_t)b * 4096 + h * 64 + wv * 16 + lane] = 1.f + beta[0] * sg;
        }
    }
}

// ------------------------------------------------------------- attention ---
// grid 256*NSPLIT; 128 thr = 2 waves x 32 q rows. Pipelined P: the LDS
// read of P(k) is issued right after its write (in-order DS queue drains
// during iter k+1's S-MFMA), and PV(k-1) runs at the top of iter k — the
// exp chain and LDS round-trip are off the PV critical path.
template <int NSPLIT>
__global__ __launch_bounds__(128, 4) void attn_kernel(
    const u16* __restrict__ Qt, const u16* __restrict__ Kt,
    const u16* __restrict__ Vm, const float* __restrict__ wkey,
    u16* __restrict__ O_part, float* __restrict__ l_part)
{
    constexpr int KT_ITERS = 64 / NSPLIT;
    __shared__ __align__(16) u16 p_s_all[2 * 32 * 68];
    const int t = threadIdx.x;
    const int qi = blockIdx.x / NSPLIT;
    const int split = blockIdx.x % NSPLIT;
    const int b = qi >> 6;
    const int n0 = (qi & 63) << 6;
    const int wv = t >> 6, lane = t & 63;
    const int quad = lane >> 4, l15 = lane & 15;
    u16* p_s = p_s_all + wv * (32 * 68);

    const u16* Qb = Qt + (size_t)b * 262144;
    const u16* Kb = Kt + (size_t)b * 262144;
    const u16* Vb = Vm + (size_t)b * 262144;
    const float* wb = wkey + (size_t)b * 4096;

    bf16x8 qf[2][2];
#pragma unroll
    for (int nt = 0; nt < 2; ++nt)
#pragma unroll
        for (int h = 0; h < 2; ++h)
            qf[nt][h] = __builtin_bit_cast(bf16x8, *reinterpret_cast<const uint4*>(
                Qb + ((size_t)(((n0 >> 4) + wv * 2 + nt) * 8 + h * 4 + quad)) * 128 + l15 * 8));

    const int kt0 = split * KT_ITERS;
    uint4 kf[4][2];
    float4 wf[4];
    uint4 vf[4][2];

    auto loadK = [&](int kt) {
#pragma unroll
        for (int mt = 0; mt < 4; ++mt)
#pragma unroll
            for (int h = 0; h < 2; ++h)
                kf[mt][h] = *reinterpret_cast<const uint4*>(
                    Kb + ((size_t)((kt * 4 + mt) * 8 + h * 4 + quad)) * 128 + l15 * 8);
    };
    auto loadW = [&](int kt) {
#pragma unroll
        for (int mt = 0; mt < 4; ++mt)
            wf[mt] = *reinterpret_cast<const float4*>(wb + kt * 64 + mt * 16 + quad * 4);
    };
    auto loadV = [&](int kt) {
#pragma unroll
        for (int f = 0; f < 4; ++f)
#pragma unroll
            for (int h = 0; h < 2; ++h)
                vf[f][h] = *reinterpret_cast<const uint4*>(
                    Vb + ((size_t)((kt * 4 + f) * 8 + h * 4 + quad)) * 128 + l15 * 8);
    };

    loadK(kt0); loadW(kt0); loadV(kt0);

    f32x4 o[2][4];
#pragma unroll
    for (int m2 = 0; m2 < 2; ++m2)
#pragma unroll
        for (int f = 0; f < 4; ++f) o[m2][f] = (f32x4){0.f, 0.f, 0.f, 0.f};
    float l_acc[2] = {0.f, 0.f};
    bf16x8 pa[2][2];

    auto computeS = [&](f32x4 (&s)[4][2]) {
#pragma unroll
        for (int mt = 0; mt < 4; ++mt)
#pragma unroll
            for (int nt = 0; nt < 2; ++nt) {
                f32x4 a = (f32x4){0.f, 0.f, 0.f, 0.f};
                a = __builtin_amdgcn_mfma_f32_16x16x32_bf16(
                        __builtin_bit_cast(bf16x8, kf[mt][0]), qf[nt][0], a, 0, 0, 0);
                a = __builtin_amdgcn_mfma_f32_16x16x32_bf16(
                        __builtin_bit_cast(bf16x8, kf[mt][1]), qf[nt][1], a, 0, 0, 0);
                s[mt][nt] = a;
            }
    };
    auto expWrite = [&](f32x4 (&s)[4][2]) {
        const float OFF = 17.3123405f;   // 12 * log2(e); Q pre-scaled by log2e
#pragma unroll
        for (int mt = 0; mt < 4; ++mt) {
            const float* wfp = reinterpret_cast<const float*>(&wf[mt]);
#pragma unroll
            for (int nt = 0; nt < 2; ++nt) {
                float p0 = exp2f(s[mt][nt][0] - OFF) * wfp[0];
                float p1 = exp2f(s[mt][nt][1] - OFF) * wfp[1];
                float p2 = exp2f(s[mt][nt][2] - OFF) * wfp[2];
                float p3 = exp2f(s[mt][nt][3] - OFF) * wfp[3];
                l_acc[nt] += (p0 + p1) + (p2 + p3);
                unsigned u0 = __builtin_bit_cast(unsigned, p0);
                unsigned u1 = __builtin_bit_cast(unsigned, p1);
                unsigned u2 = __builtin_bit_cast(unsigned, p2);
                unsigned u3 = __builtin_bit_cast(unsigned, p3);
                uint2 packed;
                packed.x = (u0 >> 16) | (u1 & 0xFFFF0000u);
                packed.y = (u2 >> 16) | (u3 & 0xFFFF0000u);
                *reinterpret_cast<uint2*>(
                    &p_s[(nt * 16 + l15) * 68 + mt * 16 + quad * 4]) = packed;
            }
        }
    };
    auto readPa = [&]() {
#pragma unroll
        for (int m2 = 0; m2 < 2; ++m2)
#pragma unroll
            for (int h = 0; h < 2; ++h) {
                uint2 lo = *reinterpret_cast<const uint2*>(
                    &p_s[(m2 * 16 + l15) * 68 + h * 32 + quad * 8]);
                uint2 hi = *reinterpret_cast<const uint2*>(
                    &p_s[(m2 * 16 + l15) * 68 + h * 32 + quad * 8 + 4]);
                uint4 c4; c4.x = lo.x; c4.y = lo.y; c4.z = hi.x; c4.w = hi.y;
                pa[m2][h] = __builtin_bit_cast(bf16x8, c4);
            }
    };
    auto pvAcc = [&]() {
#pragma unroll
        for (int m2 = 0; m2 < 2; ++m2)
#pragma unroll
            for (int f = 0; f < 4; ++f) {
                o[m2][f] = __builtin_amdgcn_mfma_f32_16x16x32_bf16(
                    pa[m2][0], __builtin_bit_cast(bf16x8, vf[f][0]), o[m2][f], 0, 0, 0);
                o[m2][f] = __builtin_amdgcn_mfma_f32_16x16x32_bf16(
                    pa[m2][1], __builtin_bit_cast(bf16x8, vf[f][1]), o[m2][f], 0, 0, 0);
            }
    };

    {   // k = kt0: S, exp, write, read-issue (no PV yet)
        f32x4 s[4][2];
        computeS(s);
        loadK(kt0 + 1 < kt0 + KT_ITERS ? kt0 + 1 : kt0);
        expWrite(s);
        loadW(kt0 + 1 < kt0 + KT_ITERS ? kt0 + 1 : kt0);
        readPa();
    }
    for (int k = kt0 + 1; k < kt0 + KT_ITERS; ++k) {
        f32x4 s[4][2];
        computeS(s);                              // uses kf = K(k)
        const int ktn = (k + 1 < kt0 + KT_ITERS) ? k + 1 : kt0;
        loadK(ktn);
        pvAcc();                                  // O += P(k-1) * V(k-1)
        loadV(k);                                 // V(k) for next PV
        expWrite(s);                              // wf = w(k)
        loadW(ktn);
        readPa();                                 // issue read of P(k)
    }
    pvAcc();                                      // drain: P(last) * V(last)

    const size_t pbase = (size_t)blockIdx.x * 64;
#pragma unroll
    for (int nt = 0; nt < 2; ++nt) {
        float v = l_acc[nt];
        v += __shfl_xor(v, 16);
        v += __shfl_xor(v, 32);
        if (lane < 16) l_part[pbase + wv * 32 + nt * 16 + lane] = v;
    }
#pragma unroll
    for (int m2 = 0; m2 < 2; ++m2)
#pragma unroll
        for (int f = 0; f < 4; ++f)
#pragma unroll
            for (int r = 0; r < 4; ++r)
                O_part[(pbase + wv * 32 + m2 * 16 + quad * 4 + r) * 64 + f * 16 + l15] =
                    f2bf(o[m2][f][r]);
}

// ---------------------------------------------------------------- combine --
template <int NSPLIT>
__global__ __launch_bounds__(256) void combine_kernel(
    const u16* __restrict__ O_part, const float* __restrict__ l_part,
    const float* __restrict__ x, const float* __restrict__ g_gamma,
    float* __restrict__ out)
{
    __shared__ float ot[16 * 65];
    __shared__ float ls[16];
    const int t = threadIdx.x;
    const int b = blockIdx.x >> 8;
    const int R0 = (blockIdx.x & 255) << 4;
    const int qi = (b << 6) + (R0 >> 6);
    const int ro = R0 & 63;
    const float gamma = g_gamma[0];

    {
        const int r = t >> 4, cq = (t & 15) * 4;
        float a0 = 0.f, a1 = 0.f, a2 = 0.f, a3 = 0.f;
#pragma unroll
        for (int s4 = 0; s4 < NSPLIT; ++s4) {
            const u16* p = O_part +
                (((size_t)qi * NSPLIT + s4) * 64 + ro + r) * 64 + cq;
            uint2 u = *reinterpret_cast<const uint2*>(p);
            a0 += bf2f((u16)(u.x & 0xFFFF));
            a1 += bf2f((u16)(u.x >> 16));
            a2 += bf2f((u16)(u.y & 0xFFFF));
            a3 += bf2f((u16)(u.y >> 16));
        }
        ot[r * 65 + cq + 0] = a0;
        ot[r * 65 + cq + 1] = a1;
        ot[r * 65 + cq + 2] = a2;
        ot[r * 65 + cq + 3] = a3;
        if (t < 16) {
            float lsum = 0.f;
#pragma unroll
            for (int s4 = 0; s4 < NSPLIT; ++s4)
                lsum += l_part[((size_t)qi * NSPLIT + s4) * 64 + ro + t];
            ls[t] = gamma / fmaxf(lsum, 1e-30f);
        }
    }
    __syncthreads();
    {
        const int c = t >> 2, nseg = t & 3;
        const size_t gbase = ((size_t)(b * 64 + c)) * 4096 + R0 + nseg * 4;
        float4 xv = *reinterpret_cast<const float4*>(&x[gbase]);
        float4 rv;
        rv.x = ot[(nseg * 4 + 0) * 65 + c] * ls[nseg * 4 + 0] + xv.x;
        rv.y = ot[(nseg * 4 + 1) * 65 + c] * ls[nseg * 4 + 1] + xv.y;
        rv.z = ot[(nseg * 4 + 2) * 65 + c] * ls[nseg * 4 + 2] + xv.z;
        rv.w = ot[(nseg * 4 + 3) * 65 + c] * ls[nseg * 4 + 3] + xv.w;
        *reinterpret_cast<float4*>(&out[gbase]) = rv;
    }
}

// ---------------------------------------------------------------- launch ---
extern "C" void kernel_launch(void* const* d_in, const int* in_sizes, int n_in,
                              void* d_out, int out_size, void* d_ws, size_t ws_size,
                              hipStream_t stream) {
    const float* x      = (const float*)d_in[0];
    const float* Wq     = (const float*)d_in[1];
    const float* bq     = (const float*)d_in[2];
    const float* Wk     = (const float*)d_in[3];
    const float* bk     = (const float*)d_in[4];
    const float* Wv     = (const float*)d_in[5];
    const float* bv     = (const float*)d_in[6];
    const float* We1    = (const float*)d_in[7];
    const float* be1    = (const float*)d_in[8];
    const float* bn_w   = (const float*)d_in[9];
    const float* bn_b   = (const float*)d_in[10];
    const float* bn_mean= (const float*)d_in[11];
    const float* bn_var = (const float*)d_in[12];
    const float* We2    = (const float*)d_in[13];
    const float* be2    = (const float*)d_in[14];
    const float* gamma  = (const float*)d_in[15];
    const float* beta   = (const float*)d_in[16];

    char* ws = (char*)d_ws;
    const size_t KB = 1024, MB = 1024 * 1024;
    u16*   Qt     = (u16*)ws;                         // [0, 2 MB)
    u16*   Kt     = (u16*)(ws + 2 * MB);              // [2, 4 MB)
    u16*   Vm     = (u16*)(ws + 4 * MB);              // [4, 6 MB)
    float* wkey   = (float*)(ws + 6 * MB);            // 64 KB
    float* l_part = (float*)(ws + 6 * MB + 64 * KB);  // up to 512 KB
    u16*   O_part = (u16*)(ws + 6 * MB + 576 * KB);   // up to 16.78 MB

    const bool use8 = ws_size >= (6 * MB + 576 * KB + (size_t)2048 * 64 * 64 * 2);

    float* out = (float*)d_out;

    qkv_edge_kernel<<<dim3(512), dim3(256), 0, stream>>>(
        x, Wq, bq, Wk, bk, Wv, bv, We1, be1, bn_w, bn_b, bn_mean, bn_var,
        We2, be2, beta, Qt, Kt, Vm, wkey);
    if (use8) {
        attn_kernel<8><<<dim3(2048), dim3(128), 0, stream>>>(Qt, Kt, Vm, wkey, O_part, l_part);
        combine_kernel<8><<<dim3(1024), dim3(256), 0, stream>>>(O_part, l_part, x, gamma, out);
    } else {
        attn_kernel<4><<<dim3(1024), dim3(128), 0, stream>>>(Qt, Kt, Vm, wkey, O_part, l_part);
        combine_kernel<4><<<dim3(1024), dim3(256), 0, stream>>>(O_part, l_part, x, gamma, out);
    }
}

// Round 10
// 155.396 us; speedup vs baseline: 1.0789x; 1.0789x over previous
//
#include <hip/hip_runtime.h>
#include <hip/hip_bf16.h>

typedef unsigned short u16;
typedef __attribute__((ext_vector_type(8))) __bf16 bf16x8;
typedef __attribute__((ext_vector_type(4))) float f32x4;

// Fragment-chunk layout for Qt/Kt/Vm (per batch, 4096x64 u16):
//   element (row n, channel c) -> ((n>>4)*8 + (c>>3))*128 + (n&15)*8 + (c&7)
// MFMA fragment loads are 64 consecutive 16B chunks -> coalesced dwordx4.
// NOTE (r9 lesson): cross-block combine fused via threadfence+counter FAILED
// on HW (stale cross-XCD partial reads, absmax 0.30) — keep combine as a
// separate kernel; the launch boundary is the only safe global sync here.

__device__ __forceinline__ u16 f2bf(float f) {
    unsigned u = __builtin_bit_cast(unsigned, f);
    u += 0x7FFFu + ((u >> 16) & 1u);
    return (u16)(u >> 16);
}
__device__ __forceinline__ float bf2f(u16 v) {
    unsigned u = ((unsigned)v) << 16;
    return __builtin_bit_cast(float, u);
}

// ------------------------------------------------------------ qkv + edge ---
// grid 512:
//  bid<256:  qkv  — LDS-staged W(bf16) + x-transpose, 24 MFMAs; Q pre-scaled
//            by log2e (attn uses exp2); fragment-chunk outputs
//  bid>=256: edge — vectorized staging of 3 x-rows + We1 reorder, 36 MFMAs
__global__ __launch_bounds__(256) void qkv_edge_kernel(
    const float* __restrict__ x,
    const float* __restrict__ Wq, const float* __restrict__ bq,
    const float* __restrict__ Wk, const float* __restrict__ bk,
    const float* __restrict__ Wv, const float* __restrict__ bv,
    const float* __restrict__ We1, const float* __restrict__ be1,
    const float* __restrict__ bn_w, const float* __restrict__ bn_b,
    const float* __restrict__ bn_mean, const float* __restrict__ bn_var,
    const float* __restrict__ We2, const float* __restrict__ be2,
    const float* __restrict__ beta,
    u16* __restrict__ Qt, u16* __restrict__ Kt, u16* __restrict__ Vm,
    float* __restrict__ wkey)
{
    __shared__ __align__(16) u16 sm[33280];
    const int t = threadIdx.x;
    const int wv = t >> 6, lane = t & 63;
    const int quad = lane >> 4, l15 = lane & 15;

    if (blockIdx.x < 256) {
        // ---------------- qkv ----------------
        u16* Wl   = sm;                 // [3][64][72]
        u16* xt_s = sm + 13824;         // [64][66]
        u16* vt   = sm + 13824 + 4224;  // [64][72]
        const int b = blockIdx.x >> 6;
        const int n0 = (blockIdx.x & 63) << 6;

        const float* Wmat[3] = {Wq, Wk, Wv};
#pragma unroll
        for (int m = 0; m < 3; ++m)
#pragma unroll
            for (int i = 0; i < 4; ++i) {
                int u = t + i * 256;
                float4 w4 = *reinterpret_cast<const float4*>(Wmat[m] + u * 4);
                int row = u >> 4, col = (u & 15) * 4;
                uint2 pk;
                pk.x = (unsigned)f2bf(w4.x) | ((unsigned)f2bf(w4.y) << 16);
                pk.y = (unsigned)f2bf(w4.z) | ((unsigned)f2bf(w4.w) << 16);
                *reinterpret_cast<uint2*>(&Wl[(m * 64 + row) * 72 + col]) = pk;
            }
        for (int i = 0; i < 16; ++i) {
            int lin = t + i * 256;
            int c = lin >> 6, nn = lin & 63;
            xt_s[nn * 66 + c] = f2bf(x[(size_t)(b * 64 + c) * 4096 + n0 + nn]);
        }
        __syncthreads();

        bf16x8 bx[2];
#pragma unroll
        for (int h = 0; h < 2; ++h)
            bx[h] = *reinterpret_cast<const bf16x8*>(
                &xt_s[(wv * 16 + l15) * 66 + h * 32 + quad * 8]);

        f32x4 d[3][4];
#pragma unroll
        for (int m = 0; m < 3; ++m)
#pragma unroll
            for (int mt = 0; mt < 4; ++mt) d[m][mt] = (f32x4){0.f, 0.f, 0.f, 0.f};

#pragma unroll
        for (int h = 0; h < 2; ++h)
#pragma unroll
            for (int m = 0; m < 3; ++m)
#pragma unroll
                for (int mt = 0; mt < 4; ++mt) {
                    bf16x8 af = *reinterpret_cast<const bf16x8*>(
                        &Wl[(m * 64 + mt * 16 + l15) * 72 + h * 32 + quad * 8]);
                    d[m][mt] = __builtin_amdgcn_mfma_f32_16x16x32_bf16(af, bx[h], d[m][mt], 0, 0, 0);
                }

        const float* bias[3] = {bq, bk, bv};
        const float L2E = 1.44269504f;
#pragma unroll
        for (int m = 0; m < 3; ++m)
#pragma unroll
            for (int mt = 0; mt < 4; ++mt) {
                float4 bi = *reinterpret_cast<const float4*>(bias[m] + mt * 16 + quad * 4);
                d[m][mt][0] += bi.x; d[m][mt][1] += bi.y; d[m][mt][2] += bi.z; d[m][mt][3] += bi.w;
                if (m == 0) {
                    d[m][mt][0] *= L2E; d[m][mt][1] *= L2E;
                    d[m][mt][2] *= L2E; d[m][mt][3] *= L2E;
                }
            }

        const int rowchunk = (n0 >> 4) + wv;
#pragma unroll
        for (int m = 0; m < 2; ++m) {
            u16* base = (m == 0 ? Qt : Kt) + (size_t)b * 262144;
#pragma unroll
            for (int mt = 0; mt < 4; ++mt) {
                uint2 pk;
                pk.x = (unsigned)f2bf(d[m][mt][0]) | ((unsigned)f2bf(d[m][mt][1]) << 16);
                pk.y = (unsigned)f2bf(d[m][mt][2]) | ((unsigned)f2bf(d[m][mt][3]) << 16);
                *reinterpret_cast<uint2*>(
                    base + ((size_t)(rowchunk * 8 + mt * 2 + (quad >> 1))) * 128 +
                    l15 * 8 + (quad & 1) * 4) = pk;
            }
        }
#pragma unroll
        for (int mt = 0; mt < 4; ++mt)
#pragma unroll
            for (int r = 0; r < 4; ++r)
                vt[(mt * 16 + quad * 4 + r) * 72 + wv * 16 + l15] = f2bf(d[2][mt][r]);
        __syncthreads();
        {
            u16* Vb_st = Vm + (size_t)b * 262144;
            const int kt = n0 >> 6;
#pragma unroll
            for (int i = 0; i < 2; ++i) {
                int unit = t + i * 256;
                int f = unit >> 7, hq = (unit >> 4) & 7, cl = unit & 15;
                const u16* src = &vt[(f * 16 + cl) * 72 + hq * 8];
                uint4 v4 = *reinterpret_cast<const uint4*>(src);
                *reinterpret_cast<uint4*>(
                    Vb_st + ((size_t)((kt * 4 + f) * 8 + hq)) * 128 + cl * 8) = v4;
            }
        }
    } else {
        // ---------------- edge ----------------
        u16* Ae_s = sm;            // [32][584]
        u16* xr_s = sm + 18688;    // [3][66][72]
        const int eb = blockIdx.x - 256;
        const int b = eb >> 6, h = eb & 63;

        if (t < 192) {
            int kh = t / 64, rem = t & 63;
            int col = (rem >> 5) * 65, ci2 = (rem & 31) * 2;
            *reinterpret_cast<unsigned*>(&xr_s[(kh * 66 + col) * 72 + ci2]) = 0u;
        }
#pragma unroll
        for (int i = 0; i < 18; ++i) {
            int u = t + i * 256;
            int ch = u / 144;
            int rem = u - ch * 144;
            int p = rem >> 4, cig = (rem & 15) * 4;
            const float* src = We1 + ch * 576 + cig * 9 + p;
            float a = src[0], b2 = src[9], c2 = src[18], d2 = src[27];
            uint2 pk;
            pk.x = (unsigned)f2bf(a) | ((unsigned)f2bf(b2) << 16);
            pk.y = (unsigned)f2bf(c2) | ((unsigned)f2bf(d2) << 16);
            *reinterpret_cast<uint2*>(&Ae_s[ch * 584 + p * 64 + cig]) = pk;
        }
#pragma unroll
        for (int i = 0; i < 12; ++i) {
            int u = t + i * 256;
            int w = u & 63, cig = (u >> 6) & 15, kh = u >> 10;
            int hs = h + kh - 1;
            float v0 = 0.f, v1 = 0.f, v2 = 0.f, v3 = 0.f;
            if ((unsigned)hs < 64u) {
                const float* src = x + ((size_t)(b * 64 + cig * 4) * 64 + hs) * 64 + w;
                v0 = src[0]; v1 = src[4096]; v2 = src[8192]; v3 = src[12288];
            }
            uint2 pk;
            pk.x = (unsigned)f2bf(v0) | ((unsigned)f2bf(v1) << 16);
            pk.y = (unsigned)f2bf(v2) | ((unsigned)f2bf(v3) << 16);
            *reinterpret_cast<uint2*>(&xr_s[(kh * 66 + w + 1) * 72 + cig * 4]) = pk;
        }
        __syncthreads();

        f32x4 e[2];
        e[0] = (f32x4){0.f, 0.f, 0.f, 0.f};
        e[1] = (f32x4){0.f, 0.f, 0.f, 0.f};
#pragma unroll
        for (int p = 0; p < 9; ++p) {
            const int kh = p / 3, kw = p - kh * 3;
#pragma unroll
            for (int half = 0; half < 2; ++half) {
                bf16x8 bfr = *reinterpret_cast<const bf16x8*>(
                    &xr_s[(kh * 66 + wv * 16 + l15 + kw) * 72 + half * 32 + quad * 8]);
#pragma unroll
                for (int mt = 0; mt < 2; ++mt) {
                    bf16x8 af = *reinterpret_cast<const bf16x8*>(
                        &Ae_s[(mt * 16 + l15) * 584 + p * 64 + half * 32 + quad * 8]);
                    e[mt] = __builtin_amdgcn_mfma_f32_16x16x32_bf16(af, bfr, e[mt], 0, 0, 0);
                }
            }
        }
        float partial = 0.f;
#pragma unroll
        for (int mt = 0; mt < 2; ++mt) {
            float4 bw = *reinterpret_cast<const float4*>(bn_w    + mt * 16 + quad * 4);
            float4 bb = *reinterpret_cast<const float4*>(bn_b    + mt * 16 + quad * 4);
            float4 bm = *reinterpret_cast<const float4*>(bn_mean + mt * 16 + quad * 4);
            float4 bv2 = *reinterpret_cast<const float4*>(bn_var + mt * 16 + quad * 4);
            float4 b1 = *reinterpret_cast<const float4*>(be1     + mt * 16 + quad * 4);
            float4 w2 = *reinterpret_cast<const float4*>(We2     + mt * 16 + quad * 4);
            float sc, sh;
            sc = bw.x * rsqrtf(bv2.x + 1e-5f); sh = (b1.x - bm.x) * sc + bb.x;
            partial += fmaxf(e[mt][0] * sc + sh, 0.f) * w2.x;
            sc = bw.y * rsqrtf(bv2.y + 1e-5f); sh = (b1.y - bm.y) * sc + bb.y;
            partial += fmaxf(e[mt][1] * sc + sh, 0.f) * w2.y;
            sc = bw.z * rsqrtf(bv2.z + 1e-5f); sh = (b1.z - bm.z) * sc + bb.z;
            partial += fmaxf(e[mt][2] * sc + sh, 0.f) * w2.z;
            sc = bw.w * rsqrtf(bv2.w + 1e-5f); sh = (b1.w - bm.w) * sc + bb.w;
            partial += fmaxf(e[mt][3] * sc + sh, 0.f) * w2.w;
        }
        partial += __shfl_xor(partial, 16);
        partial += __shfl_xor(partial, 32);
        if (lane < 16) {
            float s = partial + be2[0];
            float sg = 1.f / (1.f + __expf(-s));
            wkey[(size_t)b * 4096 + h * 64 + wv * 16 + lane] = 1.f + beta[0] * sg;
        }
    }
}

// ------------------------------------------------------------- attention ---
// grid 256*NSPLIT; 128 thr = 2 waves x 32 q rows. r7-proven loop structure
// (loads at natural positions, short live ranges, no spills — r8's explicit
// pipeline spilled to scratch and regressed). exp2 softmax with fixed offset
// (Q pre-scaled by log2e), truncation-packed P via wave-local LDS, bf16
// O_part epilogue. No barriers in k-loop.
template <int NSPLIT>
__global__ __launch_bounds__(128, 4) void attn_kernel(
    const u16* __restrict__ Qt, const u16* __restrict__ Kt,
    const u16* __restrict__ Vm, const float* __restrict__ wkey,
    u16* __restrict__ O_part, float* __restrict__ l_part)
{
    constexpr int KT_ITERS = 64 / NSPLIT;
    __shared__ __align__(16) u16 p_s_all[2 * 32 * 68];
    const int t = threadIdx.x;
    const int qi = blockIdx.x / NSPLIT;
    const int split = blockIdx.x % NSPLIT;
    const int b = qi >> 6;
    const int n0 = (qi & 63) << 6;
    const int wv = t >> 6, lane = t & 63;
    const int quad = lane >> 4, l15 = lane & 15;
    u16* p_s = p_s_all + wv * (32 * 68);

    const u16* Qb = Qt + (size_t)b * 262144;
    const u16* Kb = Kt + (size_t)b * 262144;
    const u16* Vb = Vm + (size_t)b * 262144;
    const float* wb = wkey + (size_t)b * 4096;

    bf16x8 qf[2][2];
#pragma unroll
    for (int nt = 0; nt < 2; ++nt)
#pragma unroll
        for (int h = 0; h < 2; ++h)
            qf[nt][h] = __builtin_bit_cast(bf16x8, *reinterpret_cast<const uint4*>(
                Qb + ((size_t)(((n0 >> 4) + wv * 2 + nt) * 8 + h * 4 + quad)) * 128 + l15 * 8));

    const int kt0 = split * KT_ITERS;
    uint4 kf[4][2];
    float4 wf[4];
#pragma unroll
    for (int mt = 0; mt < 4; ++mt) {
#pragma unroll
        for (int h = 0; h < 2; ++h)
            kf[mt][h] = *reinterpret_cast<const uint4*>(
                Kb + ((size_t)((kt0 * 4 + mt) * 8 + h * 4 + quad)) * 128 + l15 * 8);
        wf[mt] = *reinterpret_cast<const float4*>(wb + kt0 * 64 + mt * 16 + quad * 4);
    }

    f32x4 o[2][4];
#pragma unroll
    for (int m2 = 0; m2 < 2; ++m2)
#pragma unroll
        for (int f = 0; f < 4; ++f) o[m2][f] = (f32x4){0.f, 0.f, 0.f, 0.f};
    float l_acc[2] = {0.f, 0.f};

    for (int kt = kt0; kt < kt0 + KT_ITERS; ++kt) {
        uint4 vf[4][2];
#pragma unroll
        for (int f = 0; f < 4; ++f)
#pragma unroll
            for (int h = 0; h < 2; ++h)
                vf[f][h] = *reinterpret_cast<const uint4*>(
                    Vb + ((size_t)((kt * 4 + f) * 8 + h * 4 + quad)) * 128 + l15 * 8);

        f32x4 s[4][2];
#pragma unroll
        for (int mt = 0; mt < 4; ++mt)
#pragma unroll
            for (int nt = 0; nt < 2; ++nt) {
                f32x4 a = (f32x4){0.f, 0.f, 0.f, 0.f};
                a = __builtin_amdgcn_mfma_f32_16x16x32_bf16(
                        __builtin_bit_cast(bf16x8, kf[mt][0]), qf[nt][0], a, 0, 0, 0);
                a = __builtin_amdgcn_mfma_f32_16x16x32_bf16(
                        __builtin_bit_cast(bf16x8, kf[mt][1]), qf[nt][1], a, 0, 0, 0);
                s[mt][nt] = a;
            }

        const int ktn = (kt + 1 < kt0 + KT_ITERS) ? kt + 1 : kt0;
#pragma unroll
        for (int mt = 0; mt < 4; ++mt)
#pragma unroll
            for (int h = 0; h < 2; ++h)
                kf[mt][h] = *reinterpret_cast<const uint4*>(
                    Kb + ((size_t)((ktn * 4 + mt) * 8 + h * 4 + quad)) * 128 + l15 * 8);

        const float OFF = 17.3123405f;   // 12 * log2(e)
#pragma unroll
        for (int mt = 0; mt < 4; ++mt) {
            const float* wfp = reinterpret_cast<const float*>(&wf[mt]);
#pragma unroll
            for (int nt = 0; nt < 2; ++nt) {
                float p0 = exp2f(s[mt][nt][0] - OFF) * wfp[0];
                float p1 = exp2f(s[mt][nt][1] - OFF) * wfp[1];
                float p2 = exp2f(s[mt][nt][2] - OFF) * wfp[2];
                float p3 = exp2f(s[mt][nt][3] - OFF) * wfp[3];
                l_acc[nt] += (p0 + p1) + (p2 + p3);
                unsigned u0 = __builtin_bit_cast(unsigned, p0);
                unsigned u1 = __builtin_bit_cast(unsigned, p1);
                unsigned u2 = __builtin_bit_cast(unsigned, p2);
                unsigned u3 = __builtin_bit_cast(unsigned, p3);
                uint2 packed;
                packed.x = (u0 >> 16) | (u1 & 0xFFFF0000u);
                packed.y = (u2 >> 16) | (u3 & 0xFFFF0000u);
                *reinterpret_cast<uint2*>(
                    &p_s[(nt * 16 + l15) * 68 + mt * 16 + quad * 4]) = packed;
            }
        }

#pragma unroll
        for (int mt = 0; mt < 4; ++mt)
            wf[mt] = *reinterpret_cast<const float4*>(wb + ktn * 64 + mt * 16 + quad * 4);

        bf16x8 pa[2][2];
#pragma unroll
        for (int m2 = 0; m2 < 2; ++m2)
#pragma unroll
            for (int h = 0; h < 2; ++h) {
                uint2 lo = *reinterpret_cast<const uint2*>(
                    &p_s[(m2 * 16 + l15) * 68 + h * 32 + quad * 8]);
                uint2 hi = *reinterpret_cast<const uint2*>(
                    &p_s[(m2 * 16 + l15) * 68 + h * 32 + quad * 8 + 4]);
                uint4 c4; c4.x = lo.x; c4.y = lo.y; c4.z = hi.x; c4.w = hi.y;
                pa[m2][h] = __builtin_bit_cast(bf16x8, c4);
            }

#pragma unroll
        for (int m2 = 0; m2 < 2; ++m2)
#pragma unroll
            for (int f = 0; f < 4; ++f) {
                o[m2][f] = __builtin_amdgcn_mfma_f32_16x16x32_bf16(
                    pa[m2][0], __builtin_bit_cast(bf16x8, vf[f][0]), o[m2][f], 0, 0, 0);
                o[m2][f] = __builtin_amdgcn_mfma_f32_16x16x32_bf16(
                    pa[m2][1], __builtin_bit_cast(bf16x8, vf[f][1]), o[m2][f], 0, 0, 0);
            }
    }

    const size_t pbase = (size_t)blockIdx.x * 64;
#pragma unroll
    for (int nt = 0; nt < 2; ++nt) {
        float v = l_acc[nt];
        v += __shfl_xor(v, 16);
        v += __shfl_xor(v, 32);
        if (lane < 16) l_part[pbase + wv * 32 + nt * 16 + lane] = v;
    }
#pragma unroll
    for (int m2 = 0; m2 < 2; ++m2)
#pragma unroll
        for (int f = 0; f < 4; ++f)
#pragma unroll
            for (int r = 0; r < 4; ++r)
                O_part[(pbase + wv * 32 + m2 * 16 + quad * 4 + r) * 64 + f * 16 + l15] =
                    f2bf(o[m2][f][r]);
}

// ---------------------------------------------------------------- combine --
// grid 1024: 16 q-rows per block. Sum NSPLIT partials, normalize,
// gamma*O + x, transpose (n,c)->(c,n).
template <int NSPLIT>
__global__ __launch_bounds__(256) void combine_kernel(
    const u16* __restrict__ O_part, const float* __restrict__ l_part,
    const float* __restrict__ x, const float* __restrict__ g_gamma,
    float* __restrict__ out)
{
    __shared__ float ot[16 * 65];
    __shared__ float ls[16];
    const int t = threadIdx.x;
    const int b = blockIdx.x >> 8;
    const int R0 = (blockIdx.x & 255) << 4;
    const int qi = (b << 6) + (R0 >> 6);
    const int ro = R0 & 63;
    const float gamma = g_gamma[0];

    {
        const int r = t >> 4, cq = (t & 15) * 4;
        float a0 = 0.f, a1 = 0.f, a2 = 0.f, a3 = 0.f;
#pragma unroll
        for (int s4 = 0; s4 < NSPLIT; ++s4) {
            const u16* p = O_part +
                (((size_t)qi * NSPLIT + s4) * 64 + ro + r) * 64 + cq;
            uint2 u = *reinterpret_cast<const uint2*>(p);
            a0 += bf2f((u16)(u.x & 0xFFFF));
            a1 += bf2f((u16)(u.x >> 16));
            a2 += bf2f((u16)(u.y & 0xFFFF));
            a3 += bf2f((u16)(u.y >> 16));
        }
        ot[r * 65 + cq + 0] = a0;
        ot[r * 65 + cq + 1] = a1;
        ot[r * 65 + cq + 2] = a2;
        ot[r * 65 + cq + 3] = a3;
        if (t < 16) {
            float lsum = 0.f;
#pragma unroll
            for (int s4 = 0; s4 < NSPLIT; ++s4)
                lsum += l_part[((size_t)qi * NSPLIT + s4) * 64 + ro + t];
            ls[t] = gamma / fmaxf(lsum, 1e-30f);
        }
    }
    __syncthreads();
    {
        const int c = t >> 2, nseg = t & 3;
        const size_t gbase = ((size_t)(b * 64 + c)) * 4096 + R0 + nseg * 4;
        float4 xv = *reinterpret_cast<const float4*>(&x[gbase]);
        float4 rv;
        rv.x = ot[(nseg * 4 + 0) * 65 + c] * ls[nseg * 4 + 0] + xv.x;
        rv.y = ot[(nseg * 4 + 1) * 65 + c] * ls[nseg * 4 + 1] + xv.y;
        rv.z = ot[(nseg * 4 + 2) * 65 + c] * ls[nseg * 4 + 2] + xv.z;
        rv.w = ot[(nseg * 4 + 3) * 65 + c] * ls[nseg * 4 + 3] + xv.w;
        *reinterpret_cast<float4*>(&out[gbase]) = rv;
    }
}

// ---------------------------------------------------------------- launch ---
extern "C" void kernel_launch(void* const* d_in, const int* in_sizes, int n_in,
                              void* d_out, int out_size, void* d_ws, size_t ws_size,
                              hipStream_t stream) {
    const float* x      = (const float*)d_in[0];
    const float* Wq     = (const float*)d_in[1];
    const float* bq     = (const float*)d_in[2];
    const float* Wk     = (const float*)d_in[3];
    const float* bk     = (const float*)d_in[4];
    const float* Wv     = (const float*)d_in[5];
    const float* bv     = (const float*)d_in[6];
    const float* We1    = (const float*)d_in[7];
    const float* be1    = (const float*)d_in[8];
    const float* bn_w   = (const float*)d_in[9];
    const float* bn_b   = (const float*)d_in[10];
    const float* bn_mean= (const float*)d_in[11];
    const float* bn_var = (const float*)d_in[12];
    const float* We2    = (const float*)d_in[13];
    const float* be2    = (const float*)d_in[14];
    const float* gamma  = (const float*)d_in[15];
    const float* beta   = (const float*)d_in[16];

    char* ws = (char*)d_ws;
    const size_t KB = 1024, MB = 1024 * 1024;
    u16*   Qt     = (u16*)ws;                         // [0, 2 MB)
    u16*   Kt     = (u16*)(ws + 2 * MB);              // [2, 4 MB)
    u16*   Vm     = (u16*)(ws + 4 * MB);              // [4, 6 MB)
    float* wkey   = (float*)(ws + 6 * MB);            // 64 KB
    float* l_part = (float*)(ws + 6 * MB + 64 * KB);  // up to 512 KB
    u16*   O_part = (u16*)(ws + 6 * MB + 576 * KB);   // up to 16.78 MB

    const bool use8 = ws_size >= (6 * MB + 576 * KB + (size_t)2048 * 64 * 64 * 2);

    float* out = (float*)d_out;

    qkv_edge_kernel<<<dim3(512), dim3(256), 0, stream>>>(
        x, Wq, bq, Wk, bk, Wv, bv, We1, be1, bn_w, bn_b, bn_mean, bn_var,
        We2, be2, beta, Qt, Kt, Vm, wkey);
    if (use8) {
        attn_kernel<8><<<dim3(2048), dim3(128), 0, stream>>>(Qt, Kt, Vm, wkey, O_part, l_part);
        combine_kernel<8><<<dim3(1024), dim3(256), 0, stream>>>(O_part, l_part, x, gamma, out);
    } else {
        attn_kernel<4><<<dim3(1024), dim3(128), 0, stream>>>(Qt, Kt, Vm, wkey, O_part, l_part);
        combine_kernel<4><<<dim3(1024), dim3(256), 0, stream>>>(O_part, l_part, x, gamma, out);
    }
}

// Round 11
// 148.593 us; speedup vs baseline: 1.1283x; 1.0458x over previous
//
#include <hip/hip_runtime.h>
#include <hip/hip_bf16.h>

typedef unsigned short u16;
typedef __attribute__((ext_vector_type(8))) __bf16 bf16x8;
typedef __attribute__((ext_vector_type(4))) float f32x4;

// Fragment-chunk layout for Qt/Kt/Vm (per batch, 4096x64 u16):
//   element (row n, channel c) -> ((n>>4)*8 + (c>>3))*128 + (n&15)*8 + (c&7)
// MFMA fragment loads are 64 consecutive 16B chunks -> coalesced dwordx4.
// O_part lane-native layout (per attn block, 4096 u16):
//   offset = (((wv*2+m2)*4+f)*4+quad)*64 + l15*4, 4 packed r-values (bf16)
//   -> epilogue is 8 coalesced uint2 stores/lane (was 32 scalar stores, 2.3x
//      write amplification). combine reads the same layout coalesced.
// r9 lesson: cross-block combine via threadfence+counter FAILED on HW
// (stale cross-XCD partials) — combine stays a separate kernel.

__device__ __forceinline__ u16 f2bf(float f) {
    unsigned u = __builtin_bit_cast(unsigned, f);
    u += 0x7FFFu + ((u >> 16) & 1u);
    return (u16)(u >> 16);
}
__device__ __forceinline__ float bf2f(u16 v) {
    unsigned u = ((unsigned)v) << 16;
    return __builtin_bit_cast(float, u);
}

// ------------------------------------------------------------ qkv + edge ---
// grid 512:
//  bid<256:  qkv  — LDS-staged W(bf16) + x-transpose, 24 MFMAs; Q pre-scaled
//            by log2e (attn uses exp2); fragment-chunk outputs
//  bid>=256: edge — vectorized staging of 3 x-rows + We1 reorder, 36 MFMAs
__global__ __launch_bounds__(256) void qkv_edge_kernel(
    const float* __restrict__ x,
    const float* __restrict__ Wq, const float* __restrict__ bq,
    const float* __restrict__ Wk, const float* __restrict__ bk,
    const float* __restrict__ Wv, const float* __restrict__ bv,
    const float* __restrict__ We1, const float* __restrict__ be1,
    const float* __restrict__ bn_w, const float* __restrict__ bn_b,
    const float* __restrict__ bn_mean, const float* __restrict__ bn_var,
    const float* __restrict__ We2, const float* __restrict__ be2,
    const float* __restrict__ beta,
    u16* __restrict__ Qt, u16* __restrict__ Kt, u16* __restrict__ Vm,
    float* __restrict__ wkey)
{
    __shared__ __align__(16) u16 sm[33280];
    const int t = threadIdx.x;
    const int wv = t >> 6, lane = t & 63;
    const int quad = lane >> 4, l15 = lane & 15;

    if (blockIdx.x < 256) {
        // ---------------- qkv ----------------
        u16* Wl   = sm;                 // [3][64][72]
        u16* xt_s = sm + 13824;         // [64][66]
        u16* vt   = sm + 13824 + 4224;  // [64][72]
        const int b = blockIdx.x >> 6;
        const int n0 = (blockIdx.x & 63) << 6;

        const float* Wmat[3] = {Wq, Wk, Wv};
#pragma unroll
        for (int m = 0; m < 3; ++m)
#pragma unroll
            for (int i = 0; i < 4; ++i) {
                int u = t + i * 256;
                float4 w4 = *reinterpret_cast<const float4*>(Wmat[m] + u * 4);
                int row = u >> 4, col = (u & 15) * 4;
                uint2 pk;
                pk.x = (unsigned)f2bf(w4.x) | ((unsigned)f2bf(w4.y) << 16);
                pk.y = (unsigned)f2bf(w4.z) | ((unsigned)f2bf(w4.w) << 16);
                *reinterpret_cast<uint2*>(&Wl[(m * 64 + row) * 72 + col]) = pk;
            }
        for (int i = 0; i < 16; ++i) {
            int lin = t + i * 256;
            int c = lin >> 6, nn = lin & 63;
            xt_s[nn * 66 + c] = f2bf(x[(size_t)(b * 64 + c) * 4096 + n0 + nn]);
        }
        __syncthreads();

        bf16x8 bx[2];
#pragma unroll
        for (int h = 0; h < 2; ++h)
            bx[h] = *reinterpret_cast<const bf16x8*>(
                &xt_s[(wv * 16 + l15) * 66 + h * 32 + quad * 8]);

        f32x4 d[3][4];
#pragma unroll
        for (int m = 0; m < 3; ++m)
#pragma unroll
            for (int mt = 0; mt < 4; ++mt) d[m][mt] = (f32x4){0.f, 0.f, 0.f, 0.f};

#pragma unroll
        for (int h = 0; h < 2; ++h)
#pragma unroll
            for (int m = 0; m < 3; ++m)
#pragma unroll
                for (int mt = 0; mt < 4; ++mt) {
                    bf16x8 af = *reinterpret_cast<const bf16x8*>(
                        &Wl[(m * 64 + mt * 16 + l15) * 72 + h * 32 + quad * 8]);
                    d[m][mt] = __builtin_amdgcn_mfma_f32_16x16x32_bf16(af, bx[h], d[m][mt], 0, 0, 0);
                }

        const float* bias[3] = {bq, bk, bv};
        const float L2E = 1.44269504f;
#pragma unroll
        for (int m = 0; m < 3; ++m)
#pragma unroll
            for (int mt = 0; mt < 4; ++mt) {
                float4 bi = *reinterpret_cast<const float4*>(bias[m] + mt * 16 + quad * 4);
                d[m][mt][0] += bi.x; d[m][mt][1] += bi.y; d[m][mt][2] += bi.z; d[m][mt][3] += bi.w;
                if (m == 0) {
                    d[m][mt][0] *= L2E; d[m][mt][1] *= L2E;
                    d[m][mt][2] *= L2E; d[m][mt][3] *= L2E;
                }
            }

        const int rowchunk = (n0 >> 4) + wv;
#pragma unroll
        for (int m = 0; m < 2; ++m) {
            u16* base = (m == 0 ? Qt : Kt) + (size_t)b * 262144;
#pragma unroll
            for (int mt = 0; mt < 4; ++mt) {
                uint2 pk;
                pk.x = (unsigned)f2bf(d[m][mt][0]) | ((unsigned)f2bf(d[m][mt][1]) << 16);
                pk.y = (unsigned)f2bf(d[m][mt][2]) | ((unsigned)f2bf(d[m][mt][3]) << 16);
                *reinterpret_cast<uint2*>(
                    base + ((size_t)(rowchunk * 8 + mt * 2 + (quad >> 1))) * 128 +
                    l15 * 8 + (quad & 1) * 4) = pk;
            }
        }
#pragma unroll
        for (int mt = 0; mt < 4; ++mt)
#pragma unroll
            for (int r = 0; r < 4; ++r)
                vt[(mt * 16 + quad * 4 + r) * 72 + wv * 16 + l15] = f2bf(d[2][mt][r]);
        __syncthreads();
        {
            u16* Vb_st = Vm + (size_t)b * 262144;
            const int kt = n0 >> 6;
#pragma unroll
            for (int i = 0; i < 2; ++i) {
                int unit = t + i * 256;
                int f = unit >> 7, hq = (unit >> 4) & 7, cl = unit & 15;
                const u16* src = &vt[(f * 16 + cl) * 72 + hq * 8];
                uint4 v4 = *reinterpret_cast<const uint4*>(src);
                *reinterpret_cast<uint4*>(
                    Vb_st + ((size_t)((kt * 4 + f) * 8 + hq)) * 128 + cl * 8) = v4;
            }
        }
    } else {
        // ---------------- edge ----------------
        u16* Ae_s = sm;            // [32][584]
        u16* xr_s = sm + 18688;    // [3][66][72]
        const int eb = blockIdx.x - 256;
        const int b = eb >> 6, h = eb & 63;

        if (t < 192) {
            int kh = t / 64, rem = t & 63;
            int col = (rem >> 5) * 65, ci2 = (rem & 31) * 2;
            *reinterpret_cast<unsigned*>(&xr_s[(kh * 66 + col) * 72 + ci2]) = 0u;
        }
#pragma unroll
        for (int i = 0; i < 18; ++i) {
            int u = t + i * 256;
            int ch = u / 144;
            int rem = u - ch * 144;
            int p = rem >> 4, cig = (rem & 15) * 4;
            const float* src = We1 + ch * 576 + cig * 9 + p;
            float a = src[0], b2 = src[9], c2 = src[18], d2 = src[27];
            uint2 pk;
            pk.x = (unsigned)f2bf(a) | ((unsigned)f2bf(b2) << 16);
            pk.y = (unsigned)f2bf(c2) | ((unsigned)f2bf(d2) << 16);
            *reinterpret_cast<uint2*>(&Ae_s[ch * 584 + p * 64 + cig]) = pk;
        }
#pragma unroll
        for (int i = 0; i < 12; ++i) {
            int u = t + i * 256;
            int w = u & 63, cig = (u >> 6) & 15, kh = u >> 10;
            int hs = h + kh - 1;
            float v0 = 0.f, v1 = 0.f, v2 = 0.f, v3 = 0.f;
            if ((unsigned)hs < 64u) {
                const float* src = x + ((size_t)(b * 64 + cig * 4) * 64 + hs) * 64 + w;
                v0 = src[0]; v1 = src[4096]; v2 = src[8192]; v3 = src[12288];
            }
            uint2 pk;
            pk.x = (unsigned)f2bf(v0) | ((unsigned)f2bf(v1) << 16);
            pk.y = (unsigned)f2bf(v2) | ((unsigned)f2bf(v3) << 16);
            *reinterpret_cast<uint2*>(&xr_s[(kh * 66 + w + 1) * 72 + cig * 4]) = pk;
        }
        __syncthreads();

        f32x4 e[2];
        e[0] = (f32x4){0.f, 0.f, 0.f, 0.f};
        e[1] = (f32x4){0.f, 0.f, 0.f, 0.f};
#pragma unroll
        for (int p = 0; p < 9; ++p) {
            const int kh = p / 3, kw = p - kh * 3;
#pragma unroll
            for (int half = 0; half < 2; ++half) {
                bf16x8 bfr = *reinterpret_cast<const bf16x8*>(
                    &xr_s[(kh * 66 + wv * 16 + l15 + kw) * 72 + half * 32 + quad * 8]);
#pragma unroll
                for (int mt = 0; mt < 2; ++mt) {
                    bf16x8 af = *reinterpret_cast<const bf16x8*>(
                        &Ae_s[(mt * 16 + l15) * 584 + p * 64 + half * 32 + quad * 8]);
                    e[mt] = __builtin_amdgcn_mfma_f32_16x16x32_bf16(af, bfr, e[mt], 0, 0, 0);
                }
            }
        }
        float partial = 0.f;
#pragma unroll
        for (int mt = 0; mt < 2; ++mt) {
            float4 bw = *reinterpret_cast<const float4*>(bn_w    + mt * 16 + quad * 4);
            float4 bb = *reinterpret_cast<const float4*>(bn_b    + mt * 16 + quad * 4);
            float4 bm = *reinterpret_cast<const float4*>(bn_mean + mt * 16 + quad * 4);
            float4 bv2 = *reinterpret_cast<const float4*>(bn_var + mt * 16 + quad * 4);
            float4 b1 = *reinterpret_cast<const float4*>(be1     + mt * 16 + quad * 4);
            float4 w2 = *reinterpret_cast<const float4*>(We2     + mt * 16 + quad * 4);
            float sc, sh;
            sc = bw.x * rsqrtf(bv2.x + 1e-5f); sh = (b1.x - bm.x) * sc + bb.x;
            partial += fmaxf(e[mt][0] * sc + sh, 0.f) * w2.x;
            sc = bw.y * rsqrtf(bv2.y + 1e-5f); sh = (b1.y - bm.y) * sc + bb.y;
            partial += fmaxf(e[mt][1] * sc + sh, 0.f) * w2.y;
            sc = bw.z * rsqrtf(bv2.z + 1e-5f); sh = (b1.z - bm.z) * sc + bb.z;
            partial += fmaxf(e[mt][2] * sc + sh, 0.f) * w2.z;
            sc = bw.w * rsqrtf(bv2.w + 1e-5f); sh = (b1.w - bm.w) * sc + bb.w;
            partial += fmaxf(e[mt][3] * sc + sh, 0.f) * w2.w;
        }
        partial += __shfl_xor(partial, 16);
        partial += __shfl_xor(partial, 32);
        if (lane < 16) {
            float s = partial + be2[0];
            float sg = 1.f / (1.f + __expf(-s));
            wkey[(size_t)b * 4096 + h * 64 + wv * 16 + lane] = 1.f + beta[0] * sg;
        }
    }
}

// ------------------------------------------------------------- attention ---
// grid 256*NSPLIT; 128 thr = 2 waves x 32 q rows. r7-proven loop structure
// (loads at natural positions — r8's explicit pipeline spilled and regressed).
// exp2 softmax (Q pre-scaled by log2e), truncation-packed P via wave-local
// LDS. l computed by ones-MFMA on the idle matrix pipe (no VALU adds, no
// shuffle reduce). Vectorized lane-native O_part epilogue (8 uint2 stores).
template <int NSPLIT>
__global__ __launch_bounds__(128, 4) void attn_kernel(
    const u16* __restrict__ Qt, const u16* __restrict__ Kt,
    const u16* __restrict__ Vm, const float* __restrict__ wkey,
    u16* __restrict__ O_part, float* __restrict__ l_part)
{
    constexpr int KT_ITERS = 64 / NSPLIT;
    __shared__ __align__(16) u16 p_s_all[2 * 32 * 68];
    const int t = threadIdx.x;
    const int qi = blockIdx.x / NSPLIT;
    const int split = blockIdx.x % NSPLIT;
    const int b = qi >> 6;
    const int n0 = (qi & 63) << 6;
    const int wv = t >> 6, lane = t & 63;
    const int quad = lane >> 4, l15 = lane & 15;
    u16* p_s = p_s_all + wv * (32 * 68);

    const u16* Qb = Qt + (size_t)b * 262144;
    const u16* Kb = Kt + (size_t)b * 262144;
    const u16* Vb = Vm + (size_t)b * 262144;
    const float* wb = wkey + (size_t)b * 4096;

    bf16x8 qf[2][2];
#pragma unroll
    for (int nt = 0; nt < 2; ++nt)
#pragma unroll
        for (int h = 0; h < 2; ++h)
            qf[nt][h] = __builtin_bit_cast(bf16x8, *reinterpret_cast<const uint4*>(
                Qb + ((size_t)(((n0 >> 4) + wv * 2 + nt) * 8 + h * 4 + quad)) * 128 + l15 * 8));

    const int kt0 = split * KT_ITERS;
    uint4 kf[4][2];
    float4 wf[4];
#pragma unroll
    for (int mt = 0; mt < 4; ++mt) {
#pragma unroll
        for (int h = 0; h < 2; ++h)
            kf[mt][h] = *reinterpret_cast<const uint4*>(
                Kb + ((size_t)((kt0 * 4 + mt) * 8 + h * 4 + quad)) * 128 + l15 * 8);
        wf[mt] = *reinterpret_cast<const float4*>(wb + kt0 * 64 + mt * 16 + quad * 4);
    }

    const uint4 ones_u = {0x3F803F80u, 0x3F803F80u, 0x3F803F80u, 0x3F803F80u};
    const bf16x8 onesf = __builtin_bit_cast(bf16x8, ones_u);

    f32x4 o[2][4];
    f32x4 l5[2];
#pragma unroll
    for (int m2 = 0; m2 < 2; ++m2) {
#pragma unroll
        for (int f = 0; f < 4; ++f) o[m2][f] = (f32x4){0.f, 0.f, 0.f, 0.f};
        l5[m2] = (f32x4){0.f, 0.f, 0.f, 0.f};
    }

    for (int kt = kt0; kt < kt0 + KT_ITERS; ++kt) {
        uint4 vf[4][2];
#pragma unroll
        for (int f = 0; f < 4; ++f)
#pragma unroll
            for (int h = 0; h < 2; ++h)
                vf[f][h] = *reinterpret_cast<const uint4*>(
                    Vb + ((size_t)((kt * 4 + f) * 8 + h * 4 + quad)) * 128 + l15 * 8);

        f32x4 s[4][2];
#pragma unroll
        for (int mt = 0; mt < 4; ++mt)
#pragma unroll
            for (int nt = 0; nt < 2; ++nt) {
                f32x4 a = (f32x4){0.f, 0.f, 0.f, 0.f};
                a = __builtin_amdgcn_mfma_f32_16x16x32_bf16(
                        __builtin_bit_cast(bf16x8, kf[mt][0]), qf[nt][0], a, 0, 0, 0);
                a = __builtin_amdgcn_mfma_f32_16x16x32_bf16(
                        __builtin_bit_cast(bf16x8, kf[mt][1]), qf[nt][1], a, 0, 0, 0);
                s[mt][nt] = a;
            }

        const int ktn = (kt + 1 < kt0 + KT_ITERS) ? kt + 1 : kt0;
#pragma unroll
        for (int mt = 0; mt < 4; ++mt)
#pragma unroll
            for (int h = 0; h < 2; ++h)
                kf[mt][h] = *reinterpret_cast<const uint4*>(
                    Kb + ((size_t)((ktn * 4 + mt) * 8 + h * 4 + quad)) * 128 + l15 * 8);

        const float OFF = 17.3123405f;   // 12 * log2(e)
#pragma unroll
        for (int mt = 0; mt < 4; ++mt) {
            const float* wfp = reinterpret_cast<const float*>(&wf[mt]);
#pragma unroll
            for (int nt = 0; nt < 2; ++nt) {
                float p0 = exp2f(s[mt][nt][0] - OFF) * wfp[0];
                float p1 = exp2f(s[mt][nt][1] - OFF) * wfp[1];
                float p2 = exp2f(s[mt][nt][2] - OFF) * wfp[2];
                float p3 = exp2f(s[mt][nt][3] - OFF) * wfp[3];
                unsigned u0 = __builtin_bit_cast(unsigned, p0);
                unsigned u1 = __builtin_bit_cast(unsigned, p1);
                unsigned u2 = __builtin_bit_cast(unsigned, p2);
                unsigned u3 = __builtin_bit_cast(unsigned, p3);
                uint2 packed;
                packed.x = (u0 >> 16) | (u1 & 0xFFFF0000u);
                packed.y = (u2 >> 16) | (u3 & 0xFFFF0000u);
                *reinterpret_cast<uint2*>(
                    &p_s[(nt * 16 + l15) * 68 + mt * 16 + quad * 4]) = packed;
            }
        }

#pragma unroll
        for (int mt = 0; mt < 4; ++mt)
            wf[mt] = *reinterpret_cast<const float4*>(wb + ktn * 64 + mt * 16 + quad * 4);

        bf16x8 pa[2][2];
#pragma unroll
        for (int m2 = 0; m2 < 2; ++m2)
#pragma unroll
            for (int h = 0; h < 2; ++h) {
                uint2 lo = *reinterpret_cast<const uint2*>(
                    &p_s[(m2 * 16 + l15) * 68 + h * 32 + quad * 8]);
                uint2 hi = *reinterpret_cast<const uint2*>(
                    &p_s[(m2 * 16 + l15) * 68 + h * 32 + quad * 8 + 4]);
                uint4 c4; c4.x = lo.x; c4.y = lo.y; c4.z = hi.x; c4.w = hi.y;
                pa[m2][h] = __builtin_bit_cast(bf16x8, c4);
            }

#pragma unroll
        for (int m2 = 0; m2 < 2; ++m2) {
#pragma unroll
            for (int f = 0; f < 4; ++f) {
                o[m2][f] = __builtin_amdgcn_mfma_f32_16x16x32_bf16(
                    pa[m2][0], __builtin_bit_cast(bf16x8, vf[f][0]), o[m2][f], 0, 0, 0);
                o[m2][f] = __builtin_amdgcn_mfma_f32_16x16x32_bf16(
                    pa[m2][1], __builtin_bit_cast(bf16x8, vf[f][1]), o[m2][f], 0, 0, 0);
            }
            // l row-sums on the matrix pipe (B = ones)
            l5[m2] = __builtin_amdgcn_mfma_f32_16x16x32_bf16(pa[m2][0], onesf, l5[m2], 0, 0, 0);
            l5[m2] = __builtin_amdgcn_mfma_f32_16x16x32_bf16(pa[m2][1], onesf, l5[m2], 0, 0, 0);
        }
    }

    // epilogue: lane-native coalesced O_part; l from C-layout (uniform over l15)
    const size_t pbase = (size_t)blockIdx.x * 4096;
#pragma unroll
    for (int m2 = 0; m2 < 2; ++m2) {
        if (l15 == 0) {
            float4 lv;
            lv.x = l5[m2][0]; lv.y = l5[m2][1]; lv.z = l5[m2][2]; lv.w = l5[m2][3];
            *reinterpret_cast<float4*>(
                &l_part[(size_t)blockIdx.x * 64 + wv * 32 + m2 * 16 + quad * 4]) = lv;
        }
#pragma unroll
        for (int f = 0; f < 4; ++f) {
            uint2 pk;
            pk.x = (unsigned)f2bf(o[m2][f][0]) | ((unsigned)f2bf(o[m2][f][1]) << 16);
            pk.y = (unsigned)f2bf(o[m2][f][2]) | ((unsigned)f2bf(o[m2][f][3]) << 16);
            *reinterpret_cast<uint2*>(
                &O_part[pbase + ((((wv * 2 + m2) * 4 + f) * 4 + quad)) * 64 + l15 * 4]) = pk;
        }
    }
}

// ---------------------------------------------------------------- combine --
// grid 256: one 64-row q-group per block. Threads mapped (f,quad,l15) so every
// O_part read is a coalesced uint2 in the lane-native layout. Sum NSPLIT
// partials, normalize by l, gamma*O + x, transpose (n,c)->(c,n).
template <int NSPLIT>
__global__ __launch_bounds__(256) void combine_kernel(
    const u16* __restrict__ O_part, const float* __restrict__ l_part,
    const float* __restrict__ x, const float* __restrict__ g_gamma,
    float* __restrict__ out)
{
    __shared__ float ot[64 * 65];
    __shared__ float ls[64];
    const int t = threadIdx.x;
    const int qi = blockIdx.x;
    const int b = qi >> 6;
    const int n0 = (qi & 63) << 6;
    const int f = t >> 6, quad = (t >> 4) & 3, l15 = t & 15;
    const float gamma = g_gamma[0];

    float acc[2][2][4];
#pragma unroll
    for (int wv = 0; wv < 2; ++wv)
#pragma unroll
        for (int m2 = 0; m2 < 2; ++m2)
#pragma unroll
            for (int r = 0; r < 4; ++r) acc[wv][m2][r] = 0.f;

#pragma unroll
    for (int s4 = 0; s4 < NSPLIT; ++s4) {
        const u16* base = O_part + ((size_t)(qi * NSPLIT + s4)) * 4096;
#pragma unroll
        for (int wv = 0; wv < 2; ++wv)
#pragma unroll
            for (int m2 = 0; m2 < 2; ++m2) {
                uint2 u = *reinterpret_cast<const uint2*>(
                    base + ((((wv * 2 + m2) * 4 + f) * 4 + quad)) * 64 + l15 * 4);
                acc[wv][m2][0] += bf2f((u16)(u.x & 0xFFFF));
                acc[wv][m2][1] += bf2f((u16)(u.x >> 16));
                acc[wv][m2][2] += bf2f((u16)(u.y & 0xFFFF));
                acc[wv][m2][3] += bf2f((u16)(u.y >> 16));
            }
    }
#pragma unroll
    for (int wv = 0; wv < 2; ++wv)
#pragma unroll
        for (int m2 = 0; m2 < 2; ++m2)
#pragma unroll
            for (int r = 0; r < 4; ++r)
                ot[(wv * 32 + m2 * 16 + quad * 4 + r) * 65 + f * 16 + l15] = acc[wv][m2][r];
    if (t < 64) {
        float lsum = 0.f;
#pragma unroll
        for (int s4 = 0; s4 < NSPLIT; ++s4)
            lsum += l_part[((size_t)(qi * NSPLIT + s4)) * 64 + t];
        ls[t] = gamma / fmaxf(lsum, 1e-30f);
    }
    __syncthreads();
    {
        const int c = t >> 2, nseg = t & 3;
        const size_t gbase = ((size_t)(b * 64 + c)) * 4096 + n0 + nseg * 16;
#pragma unroll
        for (int j = 0; j < 4; ++j) {
            float4 xv = *reinterpret_cast<const float4*>(&x[gbase + j * 4]);
            float4 rv;
            int nl = nseg * 16 + j * 4;
            rv.x = ot[(nl + 0) * 65 + c] * ls[nl + 0] + xv.x;
            rv.y = ot[(nl + 1) * 65 + c] * ls[nl + 1] + xv.y;
            rv.z = ot[(nl + 2) * 65 + c] * ls[nl + 2] + xv.z;
            rv.w = ot[(nl + 3) * 65 + c] * ls[nl + 3] + xv.w;
            *reinterpret_cast<float4*>(&out[gbase + j * 4]) = rv;
        }
    }
}

// ---------------------------------------------------------------- launch ---
extern "C" void kernel_launch(void* const* d_in, const int* in_sizes, int n_in,
                              void* d_out, int out_size, void* d_ws, size_t ws_size,
                              hipStream_t stream) {
    const float* x      = (const float*)d_in[0];
    const float* Wq     = (const float*)d_in[1];
    const float* bq     = (const float*)d_in[2];
    const float* Wk     = (const float*)d_in[3];
    const float* bk     = (const float*)d_in[4];
    const float* Wv     = (const float*)d_in[5];
    const float* bv     = (const float*)d_in[6];
    const float* We1    = (const float*)d_in[7];
    const float* be1    = (const float*)d_in[8];
    const float* bn_w   = (const float*)d_in[9];
    const float* bn_b   = (const float*)d_in[10];
    const float* bn_mean= (const float*)d_in[11];
    const float* bn_var = (const float*)d_in[12];
    const float* We2    = (const float*)d_in[13];
    const float* be2    = (const float*)d_in[14];
    const float* gamma  = (const float*)d_in[15];
    const float* beta   = (const float*)d_in[16];

    char* ws = (char*)d_ws;
    const size_t KB = 1024, MB = 1024 * 1024;
    u16*   Qt     = (u16*)ws;                         // [0, 2 MB)
    u16*   Kt     = (u16*)(ws + 2 * MB);              // [2, 4 MB)
    u16*   Vm     = (u16*)(ws + 4 * MB);              // [4, 6 MB)
    float* wkey   = (float*)(ws + 6 * MB);            // 64 KB
    float* l_part = (float*)(ws + 6 * MB + 64 * KB);  // up to 512 KB
    u16*   O_part = (u16*)(ws + 6 * MB + 576 * KB);   // up to 16.78 MB

    const bool use8 = ws_size >= (6 * MB + 576 * KB + (size_t)2048 * 64 * 64 * 2);

    float* out = (float*)d_out;

    qkv_edge_kernel<<<dim3(512), dim3(256), 0, stream>>>(
        x, Wq, bq, Wk, bk, Wv, bv, We1, be1, bn_w, bn_b, bn_mean, bn_var,
        We2, be2, beta, Qt, Kt, Vm, wkey);
    if (use8) {
        attn_kernel<8><<<dim3(2048), dim3(128), 0, stream>>>(Qt, Kt, Vm, wkey, O_part, l_part);
        combine_kernel<8><<<dim3(256), dim3(256), 0, stream>>>(O_part, l_part, x, gamma, out);
    } else {
        attn_kernel<4><<<dim3(1024), dim3(128), 0, stream>>>(Qt, Kt, Vm, wkey, O_part, l_part);
        combine_kernel<4><<<dim3(256), dim3(256), 0, stream>>>(O_part, l_part, x, gamma, out);
    }
}

// Round 13
// 140.131 us; speedup vs baseline: 1.1965x; 1.0604x over previous
//
#include <hip/hip_runtime.h>
#include <hip/hip_bf16.h>

typedef unsigned short u16;
typedef __attribute__((ext_vector_type(8))) __bf16 bf16x8;
typedef __attribute__((ext_vector_type(4))) float f32x4;

// Fragment-chunk layout for Qt/Kt/Vm (per batch, 4096x64 u16):
//   element (row n, channel c) -> ((n>>4)*8 + (c>>3))*128 + (n&15)*8 + (c&7)
// attn computes O^T = V * P^T with no LDS: P's B-operand is gathered from the
// S^T C-layout registers. CORRECTNESS NOTE (r12 bug): the mt-half selection
// depends on the TARGET lane's quad>>1, so both mt candidates must be
// shuffled and the select done AFTER the shuffle (source lane's own quad>>1
// differs for quads 1,2).
// r9 lesson: cross-block combine via threadfence+counter FAILED on HW
// (stale cross-XCD partials) — combine stays a separate kernel.

__device__ __forceinline__ u16 f2bf(float f) {
    unsigned u = __builtin_bit_cast(unsigned, f);
    u += 0x7FFFu + ((u >> 16) & 1u);
    return (u16)(u >> 16);
}
__device__ __forceinline__ float bf2f(u16 v) {
    unsigned u = ((unsigned)v) << 16;
    return __builtin_bit_cast(float, u);
}

// ------------------------------------------------------------ qkv + edge ---
__global__ __launch_bounds__(256) void qkv_edge_kernel(
    const float* __restrict__ x,
    const float* __restrict__ Wq, const float* __restrict__ bq,
    const float* __restrict__ Wk, const float* __restrict__ bk,
    const float* __restrict__ Wv, const float* __restrict__ bv,
    const float* __restrict__ We1, const float* __restrict__ be1,
    const float* __restrict__ bn_w, const float* __restrict__ bn_b,
    const float* __restrict__ bn_mean, const float* __restrict__ bn_var,
    const float* __restrict__ We2, const float* __restrict__ be2,
    const float* __restrict__ beta,
    u16* __restrict__ Qt, u16* __restrict__ Kt, u16* __restrict__ Vm,
    float* __restrict__ wkey)
{
    __shared__ __align__(16) u16 sm[33280];
    const int t = threadIdx.x;
    const int wv = t >> 6, lane = t & 63;
    const int quad = lane >> 4, l15 = lane & 15;

    if (blockIdx.x < 256) {
        // ---------------- qkv ----------------
        u16* Wl   = sm;                 // [3][64][72]
        u16* xt_s = sm + 13824;         // [64][66]
        u16* vt   = sm + 13824 + 4224;  // [64][72]
        const int b = blockIdx.x >> 6;
        const int n0 = (blockIdx.x & 63) << 6;

        const float* Wmat[3] = {Wq, Wk, Wv};
#pragma unroll
        for (int m = 0; m < 3; ++m)
#pragma unroll
            for (int i = 0; i < 4; ++i) {
                int u = t + i * 256;
                float4 w4 = *reinterpret_cast<const float4*>(Wmat[m] + u * 4);
                int row = u >> 4, col = (u & 15) * 4;
                uint2 pk;
                pk.x = (unsigned)f2bf(w4.x) | ((unsigned)f2bf(w4.y) << 16);
                pk.y = (unsigned)f2bf(w4.z) | ((unsigned)f2bf(w4.w) << 16);
                *reinterpret_cast<uint2*>(&Wl[(m * 64 + row) * 72 + col]) = pk;
            }
        for (int i = 0; i < 16; ++i) {
            int lin = t + i * 256;
            int c = lin >> 6, nn = lin & 63;
            xt_s[nn * 66 + c] = f2bf(x[(size_t)(b * 64 + c) * 4096 + n0 + nn]);
        }
        __syncthreads();

        bf16x8 bx[2];
#pragma unroll
        for (int h = 0; h < 2; ++h)
            bx[h] = *reinterpret_cast<const bf16x8*>(
                &xt_s[(wv * 16 + l15) * 66 + h * 32 + quad * 8]);

        f32x4 d[3][4];
#pragma unroll
        for (int m = 0; m < 3; ++m)
#pragma unroll
            for (int mt = 0; mt < 4; ++mt) d[m][mt] = (f32x4){0.f, 0.f, 0.f, 0.f};

#pragma unroll
        for (int h = 0; h < 2; ++h)
#pragma unroll
            for (int m = 0; m < 3; ++m)
#pragma unroll
                for (int mt = 0; mt < 4; ++mt) {
                    bf16x8 af = *reinterpret_cast<const bf16x8*>(
                        &Wl[(m * 64 + mt * 16 + l15) * 72 + h * 32 + quad * 8]);
                    d[m][mt] = __builtin_amdgcn_mfma_f32_16x16x32_bf16(af, bx[h], d[m][mt], 0, 0, 0);
                }

        const float* bias[3] = {bq, bk, bv};
        const float L2E = 1.44269504f;
#pragma unroll
        for (int m = 0; m < 3; ++m)
#pragma unroll
            for (int mt = 0; mt < 4; ++mt) {
                float4 bi = *reinterpret_cast<const float4*>(bias[m] + mt * 16 + quad * 4);
                d[m][mt][0] += bi.x; d[m][mt][1] += bi.y; d[m][mt][2] += bi.z; d[m][mt][3] += bi.w;
                if (m == 0) {
                    d[m][mt][0] *= L2E; d[m][mt][1] *= L2E;
                    d[m][mt][2] *= L2E; d[m][mt][3] *= L2E;
                }
            }

        const int rowchunk = (n0 >> 4) + wv;
#pragma unroll
        for (int m = 0; m < 2; ++m) {
            u16* base = (m == 0 ? Qt : Kt) + (size_t)b * 262144;
#pragma unroll
            for (int mt = 0; mt < 4; ++mt) {
                uint2 pk;
                pk.x = (unsigned)f2bf(d[m][mt][0]) | ((unsigned)f2bf(d[m][mt][1]) << 16);
                pk.y = (unsigned)f2bf(d[m][mt][2]) | ((unsigned)f2bf(d[m][mt][3]) << 16);
                *reinterpret_cast<uint2*>(
                    base + ((size_t)(rowchunk * 8 + mt * 2 + (quad >> 1))) * 128 +
                    l15 * 8 + (quad & 1) * 4) = pk;
            }
        }
#pragma unroll
        for (int mt = 0; mt < 4; ++mt)
#pragma unroll
            for (int r = 0; r < 4; ++r)
                vt[(mt * 16 + quad * 4 + r) * 72 + wv * 16 + l15] = f2bf(d[2][mt][r]);
        __syncthreads();
        {
            u16* Vb_st = Vm + (size_t)b * 262144;
            const int kt = n0 >> 6;
#pragma unroll
            for (int i = 0; i < 2; ++i) {
                int unit = t + i * 256;
                int f = unit >> 7, hq = (unit >> 4) & 7, cl = unit & 15;
                const u16* src = &vt[(f * 16 + cl) * 72 + hq * 8];
                uint4 v4 = *reinterpret_cast<const uint4*>(src);
                *reinterpret_cast<uint4*>(
                    Vb_st + ((size_t)((kt * 4 + f) * 8 + hq)) * 128 + cl * 8) = v4;
            }
        }
    } else {
        // ---------------- edge ----------------
        u16* Ae_s = sm;            // [32][584]
        u16* xr_s = sm + 18688;    // [3][66][72]
        const int eb = blockIdx.x - 256;
        const int b = eb >> 6, h = eb & 63;

        if (t < 192) {
            int kh = t / 64, rem = t & 63;
            int col = (rem >> 5) * 65, ci2 = (rem & 31) * 2;
            *reinterpret_cast<unsigned*>(&xr_s[(kh * 66 + col) * 72 + ci2]) = 0u;
        }
#pragma unroll
        for (int i = 0; i < 18; ++i) {
            int u = t + i * 256;
            int ch = u / 144;
            int rem = u - ch * 144;
            int p = rem >> 4, cig = (rem & 15) * 4;
            const float* src = We1 + ch * 576 + cig * 9 + p;
            float a = src[0], b2 = src[9], c2 = src[18], d2 = src[27];
            uint2 pk;
            pk.x = (unsigned)f2bf(a) | ((unsigned)f2bf(b2) << 16);
            pk.y = (unsigned)f2bf(c2) | ((unsigned)f2bf(d2) << 16);
            *reinterpret_cast<uint2*>(&Ae_s[ch * 584 + p * 64 + cig]) = pk;
        }
#pragma unroll
        for (int i = 0; i < 12; ++i) {
            int u = t + i * 256;
            int w = u & 63, cig = (u >> 6) & 15, kh = u >> 10;
            int hs = h + kh - 1;
            float v0 = 0.f, v1 = 0.f, v2 = 0.f, v3 = 0.f;
            if ((unsigned)hs < 64u) {
                const float* src = x + ((size_t)(b * 64 + cig * 4) * 64 + hs) * 64 + w;
                v0 = src[0]; v1 = src[4096]; v2 = src[8192]; v3 = src[12288];
            }
            uint2 pk;
            pk.x = (unsigned)f2bf(v0) | ((unsigned)f2bf(v1) << 16);
            pk.y = (unsigned)f2bf(v2) | ((unsigned)f2bf(v3) << 16);
            *reinterpret_cast<uint2*>(&xr_s[(kh * 66 + w + 1) * 72 + cig * 4]) = pk;
        }
        __syncthreads();

        f32x4 e[2];
        e[0] = (f32x4){0.f, 0.f, 0.f, 0.f};
        e[1] = (f32x4){0.f, 0.f, 0.f, 0.f};
#pragma unroll
        for (int p = 0; p < 9; ++p) {
            const int kh = p / 3, kw = p - kh * 3;
#pragma unroll
            for (int half = 0; half < 2; ++half) {
                bf16x8 bfr = *reinterpret_cast<const bf16x8*>(
                    &xr_s[(kh * 66 + wv * 16 + l15 + kw) * 72 + half * 32 + quad * 8]);
#pragma unroll
                for (int mt = 0; mt < 2; ++mt) {
                    bf16x8 af = *reinterpret_cast<const bf16x8*>(
                        &Ae_s[(mt * 16 + l15) * 584 + p * 64 + half * 32 + quad * 8]);
                    e[mt] = __builtin_amdgcn_mfma_f32_16x16x32_bf16(af, bfr, e[mt], 0, 0, 0);
                }
            }
        }
        float partial = 0.f;
#pragma unroll
        for (int mt = 0; mt < 2; ++mt) {
            float4 bw = *reinterpret_cast<const float4*>(bn_w    + mt * 16 + quad * 4);
            float4 bb = *reinterpret_cast<const float4*>(bn_b    + mt * 16 + quad * 4);
            float4 bm = *reinterpret_cast<const float4*>(bn_mean + mt * 16 + quad * 4);
            float4 bv2 = *reinterpret_cast<const float4*>(bn_var + mt * 16 + quad * 4);
            float4 b1 = *reinterpret_cast<const float4*>(be1     + mt * 16 + quad * 4);
            float4 w2 = *reinterpret_cast<const float4*>(We2     + mt * 16 + quad * 4);
            float sc, sh;
            sc = bw.x * rsqrtf(bv2.x + 1e-5f); sh = (b1.x - bm.x) * sc + bb.x;
            partial += fmaxf(e[mt][0] * sc + sh, 0.f) * w2.x;
            sc = bw.y * rsqrtf(bv2.y + 1e-5f); sh = (b1.y - bm.y) * sc + bb.y;
            partial += fmaxf(e[mt][1] * sc + sh, 0.f) * w2.y;
            sc = bw.z * rsqrtf(bv2.z + 1e-5f); sh = (b1.z - bm.z) * sc + bb.z;
            partial += fmaxf(e[mt][2] * sc + sh, 0.f) * w2.z;
            sc = bw.w * rsqrtf(bv2.w + 1e-5f); sh = (b1.w - bm.w) * sc + bb.w;
            partial += fmaxf(e[mt][3] * sc + sh, 0.f) * w2.w;
        }
        partial += __shfl_xor(partial, 16);
        partial += __shfl_xor(partial, 32);
        if (lane < 16) {
            float s = partial + be2[0];
            float sg = 1.f / (1.f + __expf(-s));
            wkey[(size_t)b * 4096 + h * 64 + wv * 16 + lane] = 1.f + beta[0] * sg;
        }
    }
}

// ------------------------------------------------------------- attention ---
// grid 256*NSPLIT; 128 thr = 2 waves x 32 q rows. No LDS: P gathered from
// S^T C-layout registers — shuffle BOTH mt candidates, select after with the
// target lane's msel. O^T = V*P^T; l via ones-MFMA. exp2 softmax.
// launch_bounds (128,2): pk registers raise peak VGPR; a 4-wave/SIMD cap
// would force spills (r8 failure mode). 8 waves/CU == 16 for this kernel
// (r5/r6 evidence).
template <int NSPLIT>
__global__ __launch_bounds__(128, 2) void attn_kernel(
    const u16* __restrict__ Qt, const u16* __restrict__ Kt,
    const u16* __restrict__ Vm, const float* __restrict__ wkey,
    u16* __restrict__ O_part, float* __restrict__ l_part)
{
    constexpr int KT_ITERS = 64 / NSPLIT;
    const int t = threadIdx.x;
    const int qi = blockIdx.x / NSPLIT;
    const int split = blockIdx.x % NSPLIT;
    const int b = qi >> 6;
    const int n0 = (qi & 63) << 6;
    const int wv = t >> 6, lane = t & 63;
    const int quad = lane >> 4, l15 = lane & 15;

    // target element j of B-fragment: key = h*32 + quad*8 + j
    //   source lane   = ((quad&1)*2 + (j>=4))*16 + l15
    //   source reg    = pk[h*2 + (quad>>1)][nt], r = j&3
    const int src0 = ((quad & 1) * 2) * 16 + l15;
    const int src1 = src0 + 16;
    const bool msel = (quad >> 1) != 0;

    const u16* Qb = Qt + (size_t)b * 262144;
    const u16* Kb = Kt + (size_t)b * 262144;
    const u16* Vb = Vm + (size_t)b * 262144;
    const float* wb = wkey + (size_t)b * 4096;

    bf16x8 qf[2][2];
#pragma unroll
    for (int nt = 0; nt < 2; ++nt)
#pragma unroll
        for (int h = 0; h < 2; ++h)
            qf[nt][h] = __builtin_bit_cast(bf16x8, *reinterpret_cast<const uint4*>(
                Qb + ((size_t)(((n0 >> 4) + wv * 2 + nt) * 8 + h * 4 + quad)) * 128 + l15 * 8));

    const int kt0 = split * KT_ITERS;
    uint4 kf[4][2];
    float4 wf[4];
#pragma unroll
    for (int mt = 0; mt < 4; ++mt) {
#pragma unroll
        for (int h = 0; h < 2; ++h)
            kf[mt][h] = *reinterpret_cast<const uint4*>(
                Kb + ((size_t)((kt0 * 4 + mt) * 8 + h * 4 + quad)) * 128 + l15 * 8);
        wf[mt] = *reinterpret_cast<const float4*>(wb + kt0 * 64 + mt * 16 + quad * 4);
    }

    const uint4 ones_u = {0x3F803F80u, 0x3F803F80u, 0x3F803F80u, 0x3F803F80u};
    const bf16x8 onesf = __builtin_bit_cast(bf16x8, ones_u);

    f32x4 o[4][2];   // [fc = c-tile][nt], O^T[c][q]
    f32x4 l5[2];
#pragma unroll
    for (int fc = 0; fc < 4; ++fc)
#pragma unroll
        for (int nt = 0; nt < 2; ++nt) o[fc][nt] = (f32x4){0.f, 0.f, 0.f, 0.f};
#pragma unroll
    for (int nt = 0; nt < 2; ++nt) l5[nt] = (f32x4){0.f, 0.f, 0.f, 0.f};

    for (int kt = kt0; kt < kt0 + KT_ITERS; ++kt) {
        uint4 vf[4][2];
#pragma unroll
        for (int f = 0; f < 4; ++f)
#pragma unroll
            for (int h = 0; h < 2; ++h)
                vf[f][h] = *reinterpret_cast<const uint4*>(
                    Vb + ((size_t)((kt * 4 + f) * 8 + h * 4 + quad)) * 128 + l15 * 8);

        f32x4 s[4][2];
#pragma unroll
        for (int mt = 0; mt < 4; ++mt)
#pragma unroll
            for (int nt = 0; nt < 2; ++nt) {
                f32x4 a = (f32x4){0.f, 0.f, 0.f, 0.f};
                a = __builtin_amdgcn_mfma_f32_16x16x32_bf16(
                        __builtin_bit_cast(bf16x8, kf[mt][0]), qf[nt][0], a, 0, 0, 0);
                a = __builtin_amdgcn_mfma_f32_16x16x32_bf16(
                        __builtin_bit_cast(bf16x8, kf[mt][1]), qf[nt][1], a, 0, 0, 0);
                s[mt][nt] = a;
            }

        const int ktn = (kt + 1 < kt0 + KT_ITERS) ? kt + 1 : kt0;
#pragma unroll
        for (int mt = 0; mt < 4; ++mt)
#pragma unroll
            for (int h = 0; h < 2; ++h)
                kf[mt][h] = *reinterpret_cast<const uint4*>(
                    Kb + ((size_t)((ktn * 4 + mt) * 8 + h * 4 + quad)) * 128 + l15 * 8);

        // exp + pack (pk[mt][nt]: r=0..3 bf16, key=mt*16+quad*4+r, q=nt*16+l15)
        uint2 pk[4][2];
        const float OFF = 17.3123405f;   // 12 * log2(e)
#pragma unroll
        for (int mt = 0; mt < 4; ++mt) {
            const float* wfp = reinterpret_cast<const float*>(&wf[mt]);
#pragma unroll
            for (int nt = 0; nt < 2; ++nt) {
                float p0 = exp2f(s[mt][nt][0] - OFF) * wfp[0];
                float p1 = exp2f(s[mt][nt][1] - OFF) * wfp[1];
                float p2 = exp2f(s[mt][nt][2] - OFF) * wfp[2];
                float p3 = exp2f(s[mt][nt][3] - OFF) * wfp[3];
                unsigned u0 = __builtin_bit_cast(unsigned, p0);
                unsigned u1 = __builtin_bit_cast(unsigned, p1);
                unsigned u2 = __builtin_bit_cast(unsigned, p2);
                unsigned u3 = __builtin_bit_cast(unsigned, p3);
                pk[mt][nt].x = (u0 >> 16) | (u1 & 0xFFFF0000u);
                pk[mt][nt].y = (u2 >> 16) | (u3 & 0xFFFF0000u);
            }
        }

#pragma unroll
        for (int mt = 0; mt < 4; ++mt)
            wf[mt] = *reinterpret_cast<const float4*>(wb + ktn * 64 + mt * 16 + quad * 4);

        // gather P B-operand: shuffle both mt candidates, select after
        bf16x8 pb[2][2];   // [nt][h]
#pragma unroll
        for (int h = 0; h < 2; ++h)
#pragma unroll
            for (int nt = 0; nt < 2; ++nt) {
                unsigned a0x = (unsigned)__shfl((int)pk[h * 2][nt].x, src0, 64);
                unsigned a1x = (unsigned)__shfl((int)pk[h * 2 + 1][nt].x, src0, 64);
                unsigned a0y = (unsigned)__shfl((int)pk[h * 2][nt].y, src0, 64);
                unsigned a1y = (unsigned)__shfl((int)pk[h * 2 + 1][nt].y, src0, 64);
                unsigned a0z = (unsigned)__shfl((int)pk[h * 2][nt].x, src1, 64);
                unsigned a1z = (unsigned)__shfl((int)pk[h * 2 + 1][nt].x, src1, 64);
                unsigned a0w = (unsigned)__shfl((int)pk[h * 2][nt].y, src1, 64);
                unsigned a1w = (unsigned)__shfl((int)pk[h * 2 + 1][nt].y, src1, 64);
                uint4 g;
                g.x = msel ? a1x : a0x;
                g.y = msel ? a1y : a0y;
                g.z = msel ? a1z : a0z;
                g.w = msel ? a1w : a0w;
                pb[nt][h] = __builtin_bit_cast(bf16x8, g);
            }

        // O^T += V * P^T ; l += ones * P^T
#pragma unroll
        for (int nt = 0; nt < 2; ++nt) {
#pragma unroll
            for (int fc = 0; fc < 4; ++fc) {
                o[fc][nt] = __builtin_amdgcn_mfma_f32_16x16x32_bf16(
                    __builtin_bit_cast(bf16x8, vf[fc][0]), pb[nt][0], o[fc][nt], 0, 0, 0);
                o[fc][nt] = __builtin_amdgcn_mfma_f32_16x16x32_bf16(
                    __builtin_bit_cast(bf16x8, vf[fc][1]), pb[nt][1], o[fc][nt], 0, 0, 0);
            }
            l5[nt] = __builtin_amdgcn_mfma_f32_16x16x32_bf16(onesf, pb[nt][0], l5[nt], 0, 0, 0);
            l5[nt] = __builtin_amdgcn_mfma_f32_16x16x32_bf16(onesf, pb[nt][1], l5[nt], 0, 0, 0);
        }
    }

    // epilogue: lane holds O^T[c=fc*16+quad*4+r][q=wv*32+nt*16+l15]
    const size_t pbase = (size_t)blockIdx.x * 4096;
#pragma unroll
    for (int nt = 0; nt < 2; ++nt) {
        if (quad == 0)
            l_part[(size_t)blockIdx.x * 64 + wv * 32 + nt * 16 + l15] = l5[nt][0];
#pragma unroll
        for (int fc = 0; fc < 4; ++fc) {
            uint2 pk2;
            pk2.x = (unsigned)f2bf(o[fc][nt][0]) | ((unsigned)f2bf(o[fc][nt][1]) << 16);
            pk2.y = (unsigned)f2bf(o[fc][nt][2]) | ((unsigned)f2bf(o[fc][nt][3]) << 16);
            *reinterpret_cast<uint2*>(
                &O_part[pbase + ((((wv * 2 + nt) * 4 + fc) * 4 + quad)) * 64 + l15 * 4]) = pk2;
        }
    }
}

// ---------------------------------------------------------------- combine --
// grid 256: one 64-row q-group per block. O_part holds O^T fragments:
// chunk ((wv*2+nt)*4+fc)*4+quad, reg r = c-offset, lane dim l15 = q.
template <int NSPLIT>
__global__ __launch_bounds__(256) void combine_kernel(
    const u16* __restrict__ O_part, const float* __restrict__ l_part,
    const float* __restrict__ x, const float* __restrict__ g_gamma,
    float* __restrict__ out)
{
    __shared__ float ot[64 * 68];   // [q][c], stride 68 floats
    __shared__ float ls[64];
    const int t = threadIdx.x;
    const int qi = blockIdx.x;
    const int b = qi >> 6;
    const int n0 = (qi & 63) << 6;
    const int f = t >> 6, quad = (t >> 4) & 3, l15 = t & 15;
    const float gamma = g_gamma[0];

    float acc[2][2][4];
#pragma unroll
    for (int wv = 0; wv < 2; ++wv)
#pragma unroll
        for (int nt = 0; nt < 2; ++nt)
#pragma unroll
            for (int r = 0; r < 4; ++r) acc[wv][nt][r] = 0.f;

#pragma unroll
    for (int s4 = 0; s4 < NSPLIT; ++s4) {
        const u16* base = O_part + ((size_t)(qi * NSPLIT + s4)) * 4096;
#pragma unroll
        for (int wv = 0; wv < 2; ++wv)
#pragma unroll
            for (int nt = 0; nt < 2; ++nt) {
                uint2 u = *reinterpret_cast<const uint2*>(
                    base + ((((wv * 2 + nt) * 4 + f) * 4 + quad)) * 64 + l15 * 4);
                acc[wv][nt][0] += bf2f((u16)(u.x & 0xFFFF));
                acc[wv][nt][1] += bf2f((u16)(u.x >> 16));
                acc[wv][nt][2] += bf2f((u16)(u.y & 0xFFFF));
                acc[wv][nt][3] += bf2f((u16)(u.y >> 16));
            }
    }
#pragma unroll
    for (int wv = 0; wv < 2; ++wv)
#pragma unroll
        for (int nt = 0; nt < 2; ++nt) {
            float4 v4;
            v4.x = acc[wv][nt][0]; v4.y = acc[wv][nt][1];
            v4.z = acc[wv][nt][2]; v4.w = acc[wv][nt][3];
            *reinterpret_cast<float4*>(
                &ot[(wv * 32 + nt * 16 + l15) * 68 + f * 16 + quad * 4]) = v4;
        }
    if (t < 64) {
        float lsum = 0.f;
#pragma unroll
        for (int s4 = 0; s4 < NSPLIT; ++s4)
            lsum += l_part[((size_t)(qi * NSPLIT + s4)) * 64 + t];
        ls[t] = gamma / fmaxf(lsum, 1e-30f);
    }
    __syncthreads();
    {
        const int c = t >> 2, nseg = t & 3;
        const size_t gbase = ((size_t)(b * 64 + c)) * 4096 + n0 + nseg * 16;
#pragma unroll
        for (int j = 0; j < 4; ++j) {
            float4 xv = *reinterpret_cast<const float4*>(&x[gbase + j * 4]);
            float4 rv;
            int nl = nseg * 16 + j * 4;
            rv.x = ot[(nl + 0) * 68 + c] * ls[nl + 0] + xv.x;
            rv.y = ot[(nl + 1) * 68 + c] * ls[nl + 1] + xv.y;
            rv.z = ot[(nl + 2) * 68 + c] * ls[nl + 2] + xv.z;
            rv.w = ot[(nl + 3) * 68 + c] * ls[nl + 3] + xv.w;
            *reinterpret_cast<float4*>(&out[gbase + j * 4]) = rv;
        }
    }
}

// ---------------------------------------------------------------- launch ---
extern "C" void kernel_launch(void* const* d_in, const int* in_sizes, int n_in,
                              void* d_out, int out_size, void* d_ws, size_t ws_size,
                              hipStream_t stream) {
    const float* x      = (const float*)d_in[0];
    const float* Wq     = (const float*)d_in[1];
    const float* bq     = (const float*)d_in[2];
    const float* Wk     = (const float*)d_in[3];
    const float* bk     = (const float*)d_in[4];
    const float* Wv     = (const float*)d_in[5];
    const float* bv     = (const float*)d_in[6];
    const float* We1    = (const float*)d_in[7];
    const float* be1    = (const float*)d_in[8];
    const float* bn_w   = (const float*)d_in[9];
    const float* bn_b   = (const float*)d_in[10];
    const float* bn_mean= (const float*)d_in[11];
    const float* bn_var = (const float*)d_in[12];
    const float* We2    = (const float*)d_in[13];
    const float* be2    = (const float*)d_in[14];
    const float* gamma  = (const float*)d_in[15];
    const float* beta   = (const float*)d_in[16];

    char* ws = (char*)d_ws;
    const size_t KB = 1024, MB = 1024 * 1024;
    u16*   Qt     = (u16*)ws;                         // [0, 2 MB)
    u16*   Kt     = (u16*)(ws + 2 * MB);              // [2, 4 MB)
    u16*   Vm     = (u16*)(ws + 4 * MB);              // [4, 6 MB)
    float* wkey   = (float*)(ws + 6 * MB);            // 64 KB
    float* l_part = (float*)(ws + 6 * MB + 64 * KB);  // up to 512 KB
    u16*   O_part = (u16*)(ws + 6 * MB + 576 * KB);   // up to 16.78 MB

    const bool use8 = ws_size >= (6 * MB + 576 * KB + (size_t)2048 * 64 * 64 * 2);

    float* out = (float*)d_out;

    qkv_edge_kernel<<<dim3(512), dim3(256), 0, stream>>>(
        x, Wq, bq, Wk, bk, Wv, bv, We1, be1, bn_w, bn_b, bn_mean, bn_var,
        We2, be2, beta, Qt, Kt, Vm, wkey);
    if (use8) {
        attn_kernel<8><<<dim3(2048), dim3(128), 0, stream>>>(Qt, Kt, Vm, wkey, O_part, l_part);
        combine_kernel<8><<<dim3(256), dim3(256), 0, stream>>>(O_part, l_part, x, gamma, out);
    } else {
        attn_kernel<4><<<dim3(1024), dim3(128), 0, stream>>>(Qt, Kt, Vm, wkey, O_part, l_part);
        combine_kernel<4><<<dim3(256), dim3(256), 0, stream>>>(O_part, l_part, x, gamma, out);
    }
}

// Round 14
// 138.254 us; speedup vs baseline: 1.2127x; 1.0136x over previous
//
#include <hip/hip_runtime.h>
#include <hip/hip_bf16.h>

typedef unsigned short u16;
typedef __attribute__((ext_vector_type(8))) __bf16 bf16x8;
typedef __attribute__((ext_vector_type(4))) float f32x4;

// Fragment-chunk layout for Qt/Kt/Vm (per batch, 4096x64 u16):
//   element (row n, channel c) -> ((n>>4)*8 + (c>>3))*128 + (n&15)*8 + (c&7)
// attn computes O^T = V * P^T with no LDS: P's B-operand is gathered from the
// S^T C-layout registers. r12 bug note: the mt-half selection uses the TARGET
// lane's quad>>1 — shuffle both candidates, select after.
// r9 lesson: cross-block combine via threadfence+counter FAILED on HW
// (stale cross-XCD partials) — combine stays a separate kernel.
// r13 finding: harness ws-poison fill (256 MB, ~44 us) sits in the timed
// stream — it is the fixed floor; only attn/qkv_edge/combine are controllable.

#define NSPLIT 4

__device__ __forceinline__ u16 f2bf(float f) {
    unsigned u = __builtin_bit_cast(unsigned, f);
    u += 0x7FFFu + ((u >> 16) & 1u);
    return (u16)(u >> 16);
}
__device__ __forceinline__ float bf2f(u16 v) {
    unsigned u = ((unsigned)v) << 16;
    return __builtin_bit_cast(float, u);
}

// ------------------------------------------------------------ qkv + edge ---
__global__ __launch_bounds__(256) void qkv_edge_kernel(
    const float* __restrict__ x,
    const float* __restrict__ Wq, const float* __restrict__ bq,
    const float* __restrict__ Wk, const float* __restrict__ bk,
    const float* __restrict__ Wv, const float* __restrict__ bv,
    const float* __restrict__ We1, const float* __restrict__ be1,
    const float* __restrict__ bn_w, const float* __restrict__ bn_b,
    const float* __restrict__ bn_mean, const float* __restrict__ bn_var,
    const float* __restrict__ We2, const float* __restrict__ be2,
    const float* __restrict__ beta,
    u16* __restrict__ Qt, u16* __restrict__ Kt, u16* __restrict__ Vm,
    float* __restrict__ wkey)
{
    __shared__ __align__(16) u16 sm[33280];
    const int t = threadIdx.x;
    const int wv = t >> 6, lane = t & 63;
    const int quad = lane >> 4, l15 = lane & 15;

    if (blockIdx.x < 256) {
        // ---------------- qkv ----------------
        u16* Wl   = sm;                 // [3][64][72]
        u16* xt_s = sm + 13824;         // [64][66]
        u16* vt   = sm + 13824 + 4224;  // [64][72]
        const int b = blockIdx.x >> 6;
        const int n0 = (blockIdx.x & 63) << 6;

        const float* Wmat[3] = {Wq, Wk, Wv};
#pragma unroll
        for (int m = 0; m < 3; ++m)
#pragma unroll
            for (int i = 0; i < 4; ++i) {
                int u = t + i * 256;
                float4 w4 = *reinterpret_cast<const float4*>(Wmat[m] + u * 4);
                int row = u >> 4, col = (u & 15) * 4;
                uint2 pk;
                pk.x = (unsigned)f2bf(w4.x) | ((unsigned)f2bf(w4.y) << 16);
                pk.y = (unsigned)f2bf(w4.z) | ((unsigned)f2bf(w4.w) << 16);
                *reinterpret_cast<uint2*>(&Wl[(m * 64 + row) * 72 + col]) = pk;
            }
        for (int i = 0; i < 16; ++i) {
            int lin = t + i * 256;
            int c = lin >> 6, nn = lin & 63;
            xt_s[nn * 66 + c] = f2bf(x[(size_t)(b * 64 + c) * 4096 + n0 + nn]);
        }
        __syncthreads();

        bf16x8 bx[2];
#pragma unroll
        for (int h = 0; h < 2; ++h)
            bx[h] = *reinterpret_cast<const bf16x8*>(
                &xt_s[(wv * 16 + l15) * 66 + h * 32 + quad * 8]);

        f32x4 d[3][4];
#pragma unroll
        for (int m = 0; m < 3; ++m)
#pragma unroll
            for (int mt = 0; mt < 4; ++mt) d[m][mt] = (f32x4){0.f, 0.f, 0.f, 0.f};

#pragma unroll
        for (int h = 0; h < 2; ++h)
#pragma unroll
            for (int m = 0; m < 3; ++m)
#pragma unroll
                for (int mt = 0; mt < 4; ++mt) {
                    bf16x8 af = *reinterpret_cast<const bf16x8*>(
                        &Wl[(m * 64 + mt * 16 + l15) * 72 + h * 32 + quad * 8]);
                    d[m][mt] = __builtin_amdgcn_mfma_f32_16x16x32_bf16(af, bx[h], d[m][mt], 0, 0, 0);
                }

        const float* bias[3] = {bq, bk, bv};
        const float L2E = 1.44269504f;
#pragma unroll
        for (int m = 0; m < 3; ++m)
#pragma unroll
            for (int mt = 0; mt < 4; ++mt) {
                float4 bi = *reinterpret_cast<const float4*>(bias[m] + mt * 16 + quad * 4);
                d[m][mt][0] += bi.x; d[m][mt][1] += bi.y; d[m][mt][2] += bi.z; d[m][mt][3] += bi.w;
                if (m == 0) {
                    d[m][mt][0] *= L2E; d[m][mt][1] *= L2E;
                    d[m][mt][2] *= L2E; d[m][mt][3] *= L2E;
                }
            }

        const int rowchunk = (n0 >> 4) + wv;
#pragma unroll
        for (int m = 0; m < 2; ++m) {
            u16* base = (m == 0 ? Qt : Kt) + (size_t)b * 262144;
#pragma unroll
            for (int mt = 0; mt < 4; ++mt) {
                uint2 pk;
                pk.x = (unsigned)f2bf(d[m][mt][0]) | ((unsigned)f2bf(d[m][mt][1]) << 16);
                pk.y = (unsigned)f2bf(d[m][mt][2]) | ((unsigned)f2bf(d[m][mt][3]) << 16);
                *reinterpret_cast<uint2*>(
                    base + ((size_t)(rowchunk * 8 + mt * 2 + (quad >> 1))) * 128 +
                    l15 * 8 + (quad & 1) * 4) = pk;
            }
        }
#pragma unroll
        for (int mt = 0; mt < 4; ++mt)
#pragma unroll
            for (int r = 0; r < 4; ++r)
                vt[(mt * 16 + quad * 4 + r) * 72 + wv * 16 + l15] = f2bf(d[2][mt][r]);
        __syncthreads();
        {
            u16* Vb_st = Vm + (size_t)b * 262144;
            const int kt = n0 >> 6;
#pragma unroll
            for (int i = 0; i < 2; ++i) {
                int unit = t + i * 256;
                int f = unit >> 7, hq = (unit >> 4) & 7, cl = unit & 15;
                const u16* src = &vt[(f * 16 + cl) * 72 + hq * 8];
                uint4 v4 = *reinterpret_cast<const uint4*>(src);
                *reinterpret_cast<uint4*>(
                    Vb_st + ((size_t)((kt * 4 + f) * 8 + hq)) * 128 + cl * 8) = v4;
            }
        }
    } else {
        // ---------------- edge ----------------
        u16* Ae_s = sm;            // [32][584]
        u16* xr_s = sm + 18688;    // [3][66][72]
        const int eb = blockIdx.x - 256;
        const int b = eb >> 6, h = eb & 63;

        if (t < 192) {
            int kh = t / 64, rem = t & 63;
            int col = (rem >> 5) * 65, ci2 = (rem & 31) * 2;
            *reinterpret_cast<unsigned*>(&xr_s[(kh * 66 + col) * 72 + ci2]) = 0u;
        }
#pragma unroll
        for (int i = 0; i < 18; ++i) {
            int u = t + i * 256;
            int ch = u / 144;
            int rem = u - ch * 144;
            int p = rem >> 4, cig = (rem & 15) * 4;
            const float* src = We1 + ch * 576 + cig * 9 + p;
            float a = src[0], b2 = src[9], c2 = src[18], d2 = src[27];
            uint2 pk;
            pk.x = (unsigned)f2bf(a) | ((unsigned)f2bf(b2) << 16);
            pk.y = (unsigned)f2bf(c2) | ((unsigned)f2bf(d2) << 16);
            *reinterpret_cast<uint2*>(&Ae_s[ch * 584 + p * 64 + cig]) = pk;
        }
#pragma unroll
        for (int i = 0; i < 12; ++i) {
            int u = t + i * 256;
            int w = u & 63, cig = (u >> 6) & 15, kh = u >> 10;
            int hs = h + kh - 1;
            float v0 = 0.f, v1 = 0.f, v2 = 0.f, v3 = 0.f;
            if ((unsigned)hs < 64u) {
                const float* src = x + ((size_t)(b * 64 + cig * 4) * 64 + hs) * 64 + w;
                v0 = src[0]; v1 = src[4096]; v2 = src[8192]; v3 = src[12288];
            }
            uint2 pk;
            pk.x = (unsigned)f2bf(v0) | ((unsigned)f2bf(v1) << 16);
            pk.y = (unsigned)f2bf(v2) | ((unsigned)f2bf(v3) << 16);
            *reinterpret_cast<uint2*>(&xr_s[(kh * 66 + w + 1) * 72 + cig * 4]) = pk;
        }
        __syncthreads();

        f32x4 e[2];
        e[0] = (f32x4){0.f, 0.f, 0.f, 0.f};
        e[1] = (f32x4){0.f, 0.f, 0.f, 0.f};
#pragma unroll
        for (int p = 0; p < 9; ++p) {
            const int kh = p / 3, kw = p - kh * 3;
#pragma unroll
            for (int half = 0; half < 2; ++half) {
                bf16x8 bfr = *reinterpret_cast<const bf16x8*>(
                    &xr_s[(kh * 66 + wv * 16 + l15 + kw) * 72 + half * 32 + quad * 8]);
#pragma unroll
                for (int mt = 0; mt < 2; ++mt) {
                    bf16x8 af = *reinterpret_cast<const bf16x8*>(
                        &Ae_s[(mt * 16 + l15) * 584 + p * 64 + half * 32 + quad * 8]);
                    e[mt] = __builtin_amdgcn_mfma_f32_16x16x32_bf16(af, bfr, e[mt], 0, 0, 0);
                }
            }
        }
        float partial = 0.f;
#pragma unroll
        for (int mt = 0; mt < 2; ++mt) {
            float4 bw = *reinterpret_cast<const float4*>(bn_w    + mt * 16 + quad * 4);
            float4 bb = *reinterpret_cast<const float4*>(bn_b    + mt * 16 + quad * 4);
            float4 bm = *reinterpret_cast<const float4*>(bn_mean + mt * 16 + quad * 4);
            float4 bv2 = *reinterpret_cast<const float4*>(bn_var + mt * 16 + quad * 4);
            float4 b1 = *reinterpret_cast<const float4*>(be1     + mt * 16 + quad * 4);
            float4 w2 = *reinterpret_cast<const float4*>(We2     + mt * 16 + quad * 4);
            float sc, sh;
            sc = bw.x * rsqrtf(bv2.x + 1e-5f); sh = (b1.x - bm.x) * sc + bb.x;
            partial += fmaxf(e[mt][0] * sc + sh, 0.f) * w2.x;
            sc = bw.y * rsqrtf(bv2.y + 1e-5f); sh = (b1.y - bm.y) * sc + bb.y;
            partial += fmaxf(e[mt][1] * sc + sh, 0.f) * w2.y;
            sc = bw.z * rsqrtf(bv2.z + 1e-5f); sh = (b1.z - bm.z) * sc + bb.z;
            partial += fmaxf(e[mt][2] * sc + sh, 0.f) * w2.z;
            sc = bw.w * rsqrtf(bv2.w + 1e-5f); sh = (b1.w - bm.w) * sc + bb.w;
            partial += fmaxf(e[mt][3] * sc + sh, 0.f) * w2.w;
        }
        partial += __shfl_xor(partial, 16);
        partial += __shfl_xor(partial, 32);
        if (lane < 16) {
            float s = partial + be2[0];
            float sg = 1.f / (1.f + __expf(-s));
            wkey[(size_t)b * 4096 + h * 64 + wv * 16 + lane] = 1.f + beta[0] * sg;
        }
    }
}

// ------------------------------------------------------------- attention ---
// grid 256*NSPLIT(=1024); 128 thr = 2 waves x 32 q rows, 16 kt-iters. No LDS:
// P gathered from S^T C-layout registers (shuffle both mt candidates, select
// after with target lane's msel). O^T = V*P^T; l via ones-MFMA; exp2 softmax.
__global__ __launch_bounds__(128, 2) void attn_kernel(
    const u16* __restrict__ Qt, const u16* __restrict__ Kt,
    const u16* __restrict__ Vm, const float* __restrict__ wkey,
    u16* __restrict__ O_part, float* __restrict__ l_part)
{
    constexpr int KT_ITERS = 64 / NSPLIT;
    const int t = threadIdx.x;
    const int qi = blockIdx.x / NSPLIT;
    const int split = blockIdx.x % NSPLIT;
    const int b = qi >> 6;
    const int n0 = (qi & 63) << 6;
    const int wv = t >> 6, lane = t & 63;
    const int quad = lane >> 4, l15 = lane & 15;

    const int src0 = ((quad & 1) * 2) * 16 + l15;
    const int src1 = src0 + 16;
    const bool msel = (quad >> 1) != 0;

    const u16* Qb = Qt + (size_t)b * 262144;
    const u16* Kb = Kt + (size_t)b * 262144;
    const u16* Vb = Vm + (size_t)b * 262144;
    const float* wb = wkey + (size_t)b * 4096;

    bf16x8 qf[2][2];
#pragma unroll
    for (int nt = 0; nt < 2; ++nt)
#pragma unroll
        for (int h = 0; h < 2; ++h)
            qf[nt][h] = __builtin_bit_cast(bf16x8, *reinterpret_cast<const uint4*>(
                Qb + ((size_t)(((n0 >> 4) + wv * 2 + nt) * 8 + h * 4 + quad)) * 128 + l15 * 8));

    const int kt0 = split * KT_ITERS;
    uint4 kf[4][2];
    float4 wf[4];
#pragma unroll
    for (int mt = 0; mt < 4; ++mt) {
#pragma unroll
        for (int h = 0; h < 2; ++h)
            kf[mt][h] = *reinterpret_cast<const uint4*>(
                Kb + ((size_t)((kt0 * 4 + mt) * 8 + h * 4 + quad)) * 128 + l15 * 8);
        wf[mt] = *reinterpret_cast<const float4*>(wb + kt0 * 64 + mt * 16 + quad * 4);
    }

    const uint4 ones_u = {0x3F803F80u, 0x3F803F80u, 0x3F803F80u, 0x3F803F80u};
    const bf16x8 onesf = __builtin_bit_cast(bf16x8, ones_u);

    f32x4 o[4][2];   // [fc][nt], O^T[c][q]
    f32x4 l5[2];
#pragma unroll
    for (int fc = 0; fc < 4; ++fc)
#pragma unroll
        for (int nt = 0; nt < 2; ++nt) o[fc][nt] = (f32x4){0.f, 0.f, 0.f, 0.f};
#pragma unroll
    for (int nt = 0; nt < 2; ++nt) l5[nt] = (f32x4){0.f, 0.f, 0.f, 0.f};

    for (int kt = kt0; kt < kt0 + KT_ITERS; ++kt) {
        uint4 vf[4][2];
#pragma unroll
        for (int f = 0; f < 4; ++f)
#pragma unroll
            for (int h = 0; h < 2; ++h)
                vf[f][h] = *reinterpret_cast<const uint4*>(
                    Vb + ((size_t)((kt * 4 + f) * 8 + h * 4 + quad)) * 128 + l15 * 8);

        f32x4 s[4][2];
#pragma unroll
        for (int mt = 0; mt < 4; ++mt)
#pragma unroll
            for (int nt = 0; nt < 2; ++nt) {
                f32x4 a = (f32x4){0.f, 0.f, 0.f, 0.f};
                a = __builtin_amdgcn_mfma_f32_16x16x32_bf16(
                        __builtin_bit_cast(bf16x8, kf[mt][0]), qf[nt][0], a, 0, 0, 0);
                a = __builtin_amdgcn_mfma_f32_16x16x32_bf16(
                        __builtin_bit_cast(bf16x8, kf[mt][1]), qf[nt][1], a, 0, 0, 0);
                s[mt][nt] = a;
            }

        const int ktn = (kt + 1 < kt0 + KT_ITERS) ? kt + 1 : kt0;
#pragma unroll
        for (int mt = 0; mt < 4; ++mt)
#pragma unroll
            for (int h = 0; h < 2; ++h)
                kf[mt][h] = *reinterpret_cast<const uint4*>(
                    Kb + ((size_t)((ktn * 4 + mt) * 8 + h * 4 + quad)) * 128 + l15 * 8);

        uint2 pk[4][2];
        const float OFF = 17.3123405f;   // 12 * log2(e)
#pragma unroll
        for (int mt = 0; mt < 4; ++mt) {
            const float* wfp = reinterpret_cast<const float*>(&wf[mt]);
#pragma unroll
            for (int nt = 0; nt < 2; ++nt) {
                float p0 = exp2f(s[mt][nt][0] - OFF) * wfp[0];
                float p1 = exp2f(s[mt][nt][1] - OFF) * wfp[1];
                float p2 = exp2f(s[mt][nt][2] - OFF) * wfp[2];
                float p3 = exp2f(s[mt][nt][3] - OFF) * wfp[3];
                unsigned u0 = __builtin_bit_cast(unsigned, p0);
                unsigned u1 = __builtin_bit_cast(unsigned, p1);
                unsigned u2 = __builtin_bit_cast(unsigned, p2);
                unsigned u3 = __builtin_bit_cast(unsigned, p3);
                pk[mt][nt].x = (u0 >> 16) | (u1 & 0xFFFF0000u);
                pk[mt][nt].y = (u2 >> 16) | (u3 & 0xFFFF0000u);
            }
        }

#pragma unroll
        for (int mt = 0; mt < 4; ++mt)
            wf[mt] = *reinterpret_cast<const float4*>(wb + ktn * 64 + mt * 16 + quad * 4);

        bf16x8 pb[2][2];   // [nt][h]
#pragma unroll
        for (int h = 0; h < 2; ++h)
#pragma unroll
            for (int nt = 0; nt < 2; ++nt) {
                unsigned a0x = (unsigned)__shfl((int)pk[h * 2][nt].x, src0, 64);
                unsigned a1x = (unsigned)__shfl((int)pk[h * 2 + 1][nt].x, src0, 64);
                unsigned a0y = (unsigned)__shfl((int)pk[h * 2][nt].y, src0, 64);
                unsigned a1y = (unsigned)__shfl((int)pk[h * 2 + 1][nt].y, src0, 64);
                unsigned a0z = (unsigned)__shfl((int)pk[h * 2][nt].x, src1, 64);
                unsigned a1z = (unsigned)__shfl((int)pk[h * 2 + 1][nt].x, src1, 64);
                unsigned a0w = (unsigned)__shfl((int)pk[h * 2][nt].y, src1, 64);
                unsigned a1w = (unsigned)__shfl((int)pk[h * 2 + 1][nt].y, src1, 64);
                uint4 g;
                g.x = msel ? a1x : a0x;
                g.y = msel ? a1y : a0y;
                g.z = msel ? a1z : a0z;
                g.w = msel ? a1w : a0w;
                pb[nt][h] = __builtin_bit_cast(bf16x8, g);
            }

#pragma unroll
        for (int nt = 0; nt < 2; ++nt) {
#pragma unroll
            for (int fc = 0; fc < 4; ++fc) {
                o[fc][nt] = __builtin_amdgcn_mfma_f32_16x16x32_bf16(
                    __builtin_bit_cast(bf16x8, vf[fc][0]), pb[nt][0], o[fc][nt], 0, 0, 0);
                o[fc][nt] = __builtin_amdgcn_mfma_f32_16x16x32_bf16(
                    __builtin_bit_cast(bf16x8, vf[fc][1]), pb[nt][1], o[fc][nt], 0, 0, 0);
            }
            l5[nt] = __builtin_amdgcn_mfma_f32_16x16x32_bf16(onesf, pb[nt][0], l5[nt], 0, 0, 0);
            l5[nt] = __builtin_amdgcn_mfma_f32_16x16x32_bf16(onesf, pb[nt][1], l5[nt], 0, 0, 0);
        }
    }

    // epilogue: lane holds O^T[c=fc*16+quad*4+r][q=wv*32+nt*16+l15]
    const size_t pbase = (size_t)blockIdx.x * 4096;
#pragma unroll
    for (int nt = 0; nt < 2; ++nt) {
        if (quad == 0)
            l_part[(size_t)blockIdx.x * 64 + wv * 32 + nt * 16 + l15] = l5[nt][0];
#pragma unroll
        for (int fc = 0; fc < 4; ++fc) {
            uint2 pk2;
            pk2.x = (unsigned)f2bf(o[fc][nt][0]) | ((unsigned)f2bf(o[fc][nt][1]) << 16);
            pk2.y = (unsigned)f2bf(o[fc][nt][2]) | ((unsigned)f2bf(o[fc][nt][3]) << 16);
            *reinterpret_cast<uint2*>(
                &O_part[pbase + ((((wv * 2 + nt) * 4 + fc) * 4 + quad)) * 64 + l15 * 4]) = pk2;
        }
    }
}

// ---------------------------------------------------------------- combine --
// grid 1024: one 16-row quarter of a q-group per block (4 blocks/CU).
// quarter = (wv*2+nt) of the attn layout; rows = quarter-base + l15.
__global__ __launch_bounds__(256) void combine_kernel(
    const u16* __restrict__ O_part, const float* __restrict__ l_part,
    const float* __restrict__ x, const float* __restrict__ g_gamma,
    float* __restrict__ out)
{
    __shared__ float ot[16 * 68];   // [q-local][c]
    __shared__ float ls[16];
    const int t = threadIdx.x;
    const int qi = blockIdx.x >> 2;
    const int quarter = blockIdx.x & 3;
    const int b = qi >> 6;
    const int n0 = (qi & 63) << 6;
    const int rbase = (quarter >> 1) * 32 + (quarter & 1) * 16;
    const int f = t >> 6, quad = (t >> 4) & 3, l15 = t & 15;
    const float gamma = g_gamma[0];

    {
        float a0 = 0.f, a1 = 0.f, a2 = 0.f, a3 = 0.f;
#pragma unroll
        for (int s4 = 0; s4 < NSPLIT; ++s4) {
            const u16* base = O_part + ((size_t)(qi * NSPLIT + s4)) * 4096;
            uint2 u = *reinterpret_cast<const uint2*>(
                base + (((quarter * 4 + f) * 4 + quad)) * 64 + l15 * 4);
            a0 += bf2f((u16)(u.x & 0xFFFF));
            a1 += bf2f((u16)(u.x >> 16));
            a2 += bf2f((u16)(u.y & 0xFFFF));
            a3 += bf2f((u16)(u.y >> 16));
        }
        float4 v4; v4.x = a0; v4.y = a1; v4.z = a2; v4.w = a3;
        *reinterpret_cast<float4*>(&ot[l15 * 68 + f * 16 + quad * 4]) = v4;
        if (t < 16) {
            float lsum = 0.f;
#pragma unroll
            for (int s4 = 0; s4 < NSPLIT; ++s4)
                lsum += l_part[((size_t)(qi * NSPLIT + s4)) * 64 + rbase + t];
            ls[t] = gamma / fmaxf(lsum, 1e-30f);
        }
    }
    __syncthreads();
    {
        const int c = t >> 2, nseg = t & 3;
        const size_t gbase = ((size_t)(b * 64 + c)) * 4096 + n0 + rbase + nseg * 4;
        float4 xv = *reinterpret_cast<const float4*>(&x[gbase]);
        float4 rv;
        int nl = nseg * 4;
        rv.x = ot[(nl + 0) * 68 + c] * ls[nl + 0] + xv.x;
        rv.y = ot[(nl + 1) * 68 + c] * ls[nl + 1] + xv.y;
        rv.z = ot[(nl + 2) * 68 + c] * ls[nl + 2] + xv.z;
        rv.w = ot[(nl + 3) * 68 + c] * ls[nl + 3] + xv.w;
        *reinterpret_cast<float4*>(&out[gbase]) = rv;
    }
}

// ---------------------------------------------------------------- launch ---
extern "C" void kernel_launch(void* const* d_in, const int* in_sizes, int n_in,
                              void* d_out, int out_size, void* d_ws, size_t ws_size,
                              hipStream_t stream) {
    const float* x      = (const float*)d_in[0];
    const float* Wq     = (const float*)d_in[1];
    const float* bq     = (const float*)d_in[2];
    const float* Wk     = (const float*)d_in[3];
    const float* bk     = (const float*)d_in[4];
    const float* Wv     = (const float*)d_in[5];
    const float* bv     = (const float*)d_in[6];
    const float* We1    = (const float*)d_in[7];
    const float* be1    = (const float*)d_in[8];
    const float* bn_w   = (const float*)d_in[9];
    const float* bn_b   = (const float*)d_in[10];
    const float* bn_mean= (const float*)d_in[11];
    const float* bn_var = (const float*)d_in[12];
    const float* We2    = (const float*)d_in[13];
    const float* be2    = (const float*)d_in[14];
    const float* gamma  = (const float*)d_in[15];
    const float* beta   = (const float*)d_in[16];

    char* ws = (char*)d_ws;
    const size_t KB = 1024, MB = 1024 * 1024;
    u16*   Qt     = (u16*)ws;                         // [0, 2 MB)
    u16*   Kt     = (u16*)(ws + 2 * MB);              // [2, 4 MB)
    u16*   Vm     = (u16*)(ws + 4 * MB);              // [4, 6 MB)
    float* wkey   = (float*)(ws + 6 * MB);            // 64 KB
    float* l_part = (float*)(ws + 6 * MB + 64 * KB);  // 256 KB
    u16*   O_part = (u16*)(ws + 6 * MB + 576 * KB);   // 8.39 MB

    float* out = (float*)d_out;

    qkv_edge_kernel<<<dim3(512), dim3(256), 0, stream>>>(
        x, Wq, bq, Wk, bk, Wv, bv, We1, be1, bn_w, bn_b, bn_mean, bn_var,
        We2, be2, beta, Qt, Kt, Vm, wkey);
    attn_kernel<<<dim3(256 * NSPLIT), dim3(128), 0, stream>>>(
        Qt, Kt, Vm, wkey, O_part, l_part);
    combine_kernel<<<dim3(1024), dim3(256), 0, stream>>>(
        O_part, l_part, x, gamma, out);
}